// Round 1
// baseline (618.513 us; speedup 1.0000x reference)
//
#include <hip/hip_runtime.h>

typedef short bf16x8 __attribute__((ext_vector_type(8)));
typedef float f32x4 __attribute__((ext_vector_type(4)));
typedef unsigned short ushort8 __attribute__((ext_vector_type(8)));
typedef unsigned short ushort4v __attribute__((ext_vector_type(4)));
typedef float float4v __attribute__((ext_vector_type(4)));

__device__ __forceinline__ unsigned short f2bf(float f) {
  unsigned u = __builtin_bit_cast(unsigned, f);
  u = u + 0x7fffu + ((u >> 16) & 1u);
  return (unsigned short)(u >> 16);
}

__device__ __forceinline__ void gload16(const void* g, void* l) {
  __builtin_amdgcn_global_load_lds(
      (const __attribute__((address_space(1))) unsigned int*)g,
      (__attribute__((address_space(3))) unsigned int*)l, 16, 0, 0);
}

__device__ __forceinline__ void store_out(float* p, float v) { *p = v; }
__device__ __forceinline__ void store_out(unsigned short* p, float v) { *p = f2bf(v); }

// ---------------- fp32 -> bf16 convert (vectorized) ----------------
__global__ __launch_bounds__(256) void convert_f2b(const float* __restrict__ x,
                                                   unsigned short* __restrict__ y,
                                                   int n4) {
  int i = blockIdx.x * 256 + threadIdx.x;
  if (i >= n4) return;
  float4v v = ((const float4v*)x)[i];
  ushort4v u;
  u[0] = f2bf(v[0]); u[1] = f2bf(v[1]); u[2] = f2bf(v[2]); u[3] = f2bf(v[3]);
  ((ushort4v*)y)[i] = u;
}

// ---------------- W [K][N] fp32 -> Wt [N][K] bf16 ----------------
__global__ __launch_bounds__(256) void transpose_w(const float* __restrict__ W,
                                                   unsigned short* __restrict__ Wt) {
  __shared__ float tile[32][33];
  int bx = blockIdx.x * 32;  // col (n) base
  int by = blockIdx.y * 32;  // row (k) base
  int tx = threadIdx.x & 31;
  int ty = threadIdx.x >> 5;  // 0..7
#pragma unroll
  for (int j = 0; j < 32; j += 8)
    tile[ty + j][tx] = W[(size_t)(by + ty + j) * 1024 + bx + tx];
  __syncthreads();
#pragma unroll
  for (int j = 0; j < 32; j += 8)
    Wt[(size_t)(bx + ty + j) * 1024 + by + tx] = f2bf(tile[tx][ty + j]);
}

// ---------------- GEMM: C[M,N] = A[M,K] * Bt[N,K]^T + bias ----------------
// m97 structure: 128x128 tile, BK=32, 4 waves (2x2, 64x64 each), global_load_lds.
template <typename OT>
__global__ __launch_bounds__(256) void gemm_bt(const unsigned short* __restrict__ A,
                                               const unsigned short* __restrict__ Bt,
                                               const float* __restrict__ bias,
                                               OT* __restrict__ C, int M, int N, int K) {
  __shared__ __align__(16) unsigned short As[128 * 32];
  __shared__ __align__(16) unsigned short Bs[128 * 32];
  const int t = threadIdx.x;
  const int nb = N >> 7;
  const int bm = blockIdx.x / nb, bn = blockIdx.x % nb;
  const int lane = t & 63, wid = t >> 6;
  const int wr = wid >> 1, wc = wid & 1;
  const int lr = lane & 15, lg = lane >> 4;
  f32x4 acc[4][4] = {};
  const size_t baseA = (size_t)(bm * 128) * K;
  const size_t baseB = (size_t)(bn * 128) * K;
  const int c0 = t, c1 = t + 256;
  const int rA0 = c0 >> 2, kA0 = (c0 & 3) * 8;
  const int rA1 = c1 >> 2, kA1 = (c1 & 3) * 8;
  for (int ks = 0; ks < K; ks += 32) {
    __syncthreads();
    gload16(&A[baseA + (size_t)rA0 * K + ks + kA0], &As[c0 * 8]);
    gload16(&A[baseA + (size_t)rA1 * K + ks + kA1], &As[c1 * 8]);
    gload16(&Bt[baseB + (size_t)rA0 * K + ks + kA0], &Bs[c0 * 8]);
    gload16(&Bt[baseB + (size_t)rA1 * K + ks + kA1], &Bs[c1 * 8]);
    __syncthreads();
    bf16x8 a[4], b[4];
#pragma unroll
    for (int m = 0; m < 4; ++m)
      a[m] = *(const bf16x8*)&As[(wr * 64 + 16 * m + lr) * 32 + lg * 8];
#pragma unroll
    for (int n = 0; n < 4; ++n)
      b[n] = *(const bf16x8*)&Bs[(wc * 64 + 16 * n + lr) * 32 + lg * 8];
#pragma unroll
    for (int m = 0; m < 4; ++m)
#pragma unroll
      for (int n = 0; n < 4; ++n)
        acc[m][n] = __builtin_amdgcn_mfma_f32_16x16x32_bf16(a[m], b[n], acc[m][n], 0, 0, 0);
  }
  const int rowb = bm * 128 + wr * 64;
  const int colb = bn * 128 + wc * 64;
#pragma unroll
  for (int n = 0; n < 4; ++n) {
    int col = colb + 16 * n + lr;
    float bv = bias[col];
#pragma unroll
    for (int m = 0; m < 4; ++m) {
      int row0 = rowb + 16 * m + 4 * lg;
#pragma unroll
      for (int r = 0; r < 4; ++r) {
        float v = acc[m][n][r] + bv;
        store_out(&C[(size_t)(row0 + r) * N + col], v);
      }
    }
  }
}

// ---------------- Flash attention ----------------
// grid = 1024 blocks: bid = b*256 + h*16 + qb. 4 waves x 32 q-rows. KB=128.
// Q/K staged via global_load_lds with pre-swizzled global source (XOR chunk ^ row&7).
// V reg-transposed to Vt[64][128] (swizzled). P via swizzled LDS.
__global__ __launch_bounds__(256) void attn_kernel(const unsigned short* __restrict__ Q,
                                                   const unsigned short* __restrict__ K,
                                                   const unsigned short* __restrict__ V,
                                                   const int* __restrict__ mask,
                                                   unsigned short* __restrict__ ctx) {
  __shared__ __align__(16) unsigned short Qs[128 * 64];
  __shared__ __align__(16) unsigned short Ks[128 * 64];
  __shared__ __align__(16) unsigned short Vt[64 * 128];
  __shared__ __align__(16) unsigned short Ps[128 * 128];
  const int bid = blockIdx.x;
  const int qb = bid & 15, h = (bid >> 4) & 15, b = bid >> 8;
  const int t = threadIdx.x;
  const int lane = t & 63, wid = t >> 6;
  const int lr = lane & 15, lg = lane >> 4;
  const size_t rowQ0 = (size_t)(b * 2048 + qb * 128);
  const size_t rowK0 = (size_t)(b * 2048);
  const int hcol = h * 64;
#pragma unroll
  for (int i = 0; i < 4; ++i) {
    int c = t + 256 * i;
    int row = c >> 3, dcp = c & 7;
    int dc = dcp ^ (row & 7);
    gload16(&Q[(rowQ0 + row) * 1024 + hcol + dc * 8], &Qs[c * 8]);
  }
  float m_run[2][4], l_run[2][4];
  f32x4 o[2][4];
#pragma unroll
  for (int m = 0; m < 2; ++m)
#pragma unroll
    for (int r = 0; r < 4; ++r) { m_run[m][r] = -3e38f; l_run[m][r] = 0.f; }
#pragma unroll
  for (int m = 0; m < 2; ++m)
#pragma unroll
    for (int n = 0; n < 4; ++n) o[m][n] = (f32x4){0.f, 0.f, 0.f, 0.f};
  const int* mb = mask + b * 2048;

  for (int kb = 0; kb < 16; ++kb) {
    __syncthreads();  // prev iter's reads of Ks/Vt/Ps done; also drains Q stage on kb=0
    const size_t rk = rowK0 + kb * 128;
#pragma unroll
    for (int i = 0; i < 4; ++i) {
      int c = t + 256 * i;
      int row = c >> 3, dcp = c & 7;
      int dc = dcp ^ (row & 7);
      gload16(&K[(rk + row) * 1024 + hcol + dc * 8], &Ks[c * 8]);
    }
#pragma unroll
    for (int i = 0; i < 4; ++i) {
      int c = t + 256 * i;
      int krow = c >> 3, dc = c & 7;
      ushort8 v = *(const ushort8*)&V[(rk + krow) * 1024 + hcol + dc * 8];
#pragma unroll
      for (int j = 0; j < 8; ++j) {
        int d = dc * 8 + j;
        Vt[d * 128 + (krow ^ ((d & 7) << 3))] = v[j];
      }
    }
    __syncthreads();
    // ---- S = Q K^T ----
    bf16x8 aq[2][2];
#pragma unroll
    for (int m = 0; m < 2; ++m)
#pragma unroll
      for (int kk = 0; kk < 2; ++kk) {
        int row = wid * 32 + 16 * m + lr;
        int ch = (kk * 4 + lg) ^ (row & 7);
        aq[m][kk] = *(const bf16x8*)&Qs[row * 64 + ch * 8];
      }
    f32x4 s[2][8];
#pragma unroll
    for (int n = 0; n < 8; ++n) {
      int key = 16 * n + lr;
      int ch0 = (0 + lg) ^ (key & 7);
      int ch1 = (4 + lg) ^ (key & 7);
      bf16x8 b0 = *(const bf16x8*)&Ks[key * 64 + ch0 * 8];
      bf16x8 b1 = *(const bf16x8*)&Ks[key * 64 + ch1 * 8];
#pragma unroll
      for (int m = 0; m < 2; ++m) {
        f32x4 acc0 = __builtin_amdgcn_mfma_f32_16x16x32_bf16(aq[m][0], b0, (f32x4){0.f,0.f,0.f,0.f}, 0, 0, 0);
        s[m][n] = __builtin_amdgcn_mfma_f32_16x16x32_bf16(aq[m][1], b1, acc0, 0, 0, 0);
      }
    }
    // ---- mask ----
#pragma unroll
    for (int n = 0; n < 8; ++n) {
      int mv = mb[kb * 128 + 16 * n + lr];
      if (mv == 0) {
#pragma unroll
        for (int m = 0; m < 2; ++m)
#pragma unroll
          for (int r = 0; r < 4; ++r) s[m][n][r] = -10000.f;
      }
    }
    // ---- online softmax (rows: 16-lane-group reduce) ----
#pragma unroll
    for (int m = 0; m < 2; ++m)
#pragma unroll
      for (int r = 0; r < 4; ++r) {
        float mx = s[m][0][r];
#pragma unroll
        for (int n = 1; n < 8; ++n) mx = fmaxf(mx, s[m][n][r]);
        mx = fmaxf(mx, __shfl_xor(mx, 1));
        mx = fmaxf(mx, __shfl_xor(mx, 2));
        mx = fmaxf(mx, __shfl_xor(mx, 4));
        mx = fmaxf(mx, __shfl_xor(mx, 8));
        float mnew = fmaxf(m_run[m][r], mx);
        float corr = __expf(m_run[m][r] - mnew);
        m_run[m][r] = mnew;
        float rs = 0.f;
#pragma unroll
        for (int n = 0; n < 8; ++n) {
          float p = __expf(s[m][n][r] - mnew);
          s[m][n][r] = p;
          rs += p;
        }
        rs += __shfl_xor(rs, 1);
        rs += __shfl_xor(rs, 2);
        rs += __shfl_xor(rs, 4);
        rs += __shfl_xor(rs, 8);
        l_run[m][r] = l_run[m][r] * corr + rs;
#pragma unroll
        for (int dn = 0; dn < 4; ++dn) o[m][dn][r] *= corr;
      }
    // ---- write P (bf16, swizzled) ----
#pragma unroll
    for (int m = 0; m < 2; ++m)
#pragma unroll
      for (int r = 0; r < 4; ++r) {
        int qt = wid * 32 + 16 * m + 4 * lg + r;
        int sw = (qt & 7) << 3;
#pragma unroll
        for (int n = 0; n < 8; ++n) {
          int k = 16 * n + lr;
          Ps[qt * 128 + (k ^ sw)] = f2bf(s[m][n][r]);
        }
      }
    __syncthreads();
    // ---- O += P V ----
#pragma unroll
    for (int kk = 0; kk < 4; ++kk) {
      bf16x8 pa[2];
#pragma unroll
      for (int m = 0; m < 2; ++m) {
        int qa = wid * 32 + 16 * m + lr;
        int ch = (kk * 4 + lg) ^ (qa & 7);
        pa[m] = *(const bf16x8*)&Ps[qa * 128 + ch * 8];
      }
#pragma unroll
      for (int dn = 0; dn < 4; ++dn) {
        int d = 16 * dn + lr;
        int ch = (kk * 4 + lg) ^ (d & 7);
        bf16x8 vb = *(const bf16x8*)&Vt[d * 128 + ch * 8];
#pragma unroll
        for (int m = 0; m < 2; ++m)
          o[m][dn] = __builtin_amdgcn_mfma_f32_16x16x32_bf16(pa[m], vb, o[m][dn], 0, 0, 0);
      }
    }
  }
  // ---- epilogue ----
#pragma unroll
  for (int m = 0; m < 2; ++m)
#pragma unroll
    for (int r = 0; r < 4; ++r) {
      int qt = wid * 32 + 16 * m + 4 * lg + r;
      float inv = 1.f / l_run[m][r];
#pragma unroll
      for (int dn = 0; dn < 4; ++dn) {
        float val = o[m][dn][r] * inv;
        ctx[(rowQ0 + qt) * 1024 + hcol + 16 * dn + lr] = f2bf(val);
      }
    }
}

extern "C" void kernel_launch(void* const* d_in, const int* in_sizes, int n_in,
                              void* d_out, int out_size, void* d_ws, size_t ws_size,
                              hipStream_t stream) {
  const float* srcQ = (const float*)d_in[0];
  const float* srcK = (const float*)d_in[1];
  const float* srcV = (const float*)d_in[2];
  const int*   mask = (const int*)d_in[3];
  const float* Wq = (const float*)d_in[4];
  const float* bq = (const float*)d_in[5];
  const float* Wk = (const float*)d_in[6];
  const float* bk = (const float*)d_in[7];
  const float* Wv = (const float*)d_in[8];
  const float* bv = (const float*)d_in[9];
  const float* Wo = (const float*)d_in[10];
  const float* bo = (const float*)d_in[11];
  float* out = (float*)d_out;

  const int M = 8192, N = 1024, Kd = 1024;
  char* ws = (char*)d_ws;
  unsigned short* Xb  = (unsigned short*)(ws);                       // 16 MiB (also ctx later)
  unsigned short* Qb  = (unsigned short*)(ws + (size_t)(16 << 20));  // 16 MiB
  unsigned short* Kb  = (unsigned short*)(ws + (size_t)(32 << 20));  // 16 MiB
  unsigned short* Vb  = (unsigned short*)(ws + (size_t)(48 << 20));  // 16 MiB
  unsigned short* Wt  = (unsigned short*)(ws + (size_t)(64 << 20));  // 4 x 2 MiB
  unsigned short* ctx = Xb;

  dim3 tb(256);
  dim3 tg(32, 32);
  transpose_w<<<tg, tb, 0, stream>>>(Wq, Wt + 0 * (1 << 20));
  transpose_w<<<tg, tb, 0, stream>>>(Wk, Wt + 1 * (1 << 20));
  transpose_w<<<tg, tb, 0, stream>>>(Wv, Wt + 2 * (1 << 20));
  transpose_w<<<tg, tb, 0, stream>>>(Wo, Wt + 3 * (1 << 20));

  const int n4 = M * N / 4;  // 2097152
  const int gemm_grid = (M / 128) * (N / 128);  // 512

  convert_f2b<<<n4 / 256, 256, 0, stream>>>(srcQ, Xb, n4);
  gemm_bt<unsigned short><<<gemm_grid, 256, 0, stream>>>(Xb, Wt + 0 * (1 << 20), bq, Qb, M, N, Kd);
  convert_f2b<<<n4 / 256, 256, 0, stream>>>(srcK, Xb, n4);
  gemm_bt<unsigned short><<<gemm_grid, 256, 0, stream>>>(Xb, Wt + 1 * (1 << 20), bk, Kb, M, N, Kd);
  convert_f2b<<<n4 / 256, 256, 0, stream>>>(srcV, Xb, n4);
  gemm_bt<unsigned short><<<gemm_grid, 256, 0, stream>>>(Xb, Wt + 2 * (1 << 20), bv, Vb, M, N, Kd);

  attn_kernel<<<1024, 256, 0, stream>>>(Qb, Kb, Vb, mask, ctx);

  gemm_bt<float><<<gemm_grid, 256, 0, stream>>>(ctx, Wt + 3 * (1 << 20), bo, out, M, N, Kd);
}

// Round 3
// 415.443 us; speedup vs baseline: 1.4888x; 1.4888x over previous
//
#include <hip/hip_runtime.h>

typedef short bf16x8 __attribute__((ext_vector_type(8)));
typedef short bf16x4 __attribute__((ext_vector_type(4)));
typedef float f32x4 __attribute__((ext_vector_type(4)));
typedef unsigned short ushort8 __attribute__((ext_vector_type(8)));
typedef unsigned short ushort4v __attribute__((ext_vector_type(4)));
typedef unsigned int uint4v __attribute__((ext_vector_type(4)));
typedef float float4v __attribute__((ext_vector_type(4)));

#define LOG2E 1.4426950408889634f
#define MASKED_VAL -14426.950408889634f  /* -10000 * log2(e) */

__device__ __forceinline__ unsigned short f2bf(float f) {
  unsigned u = __builtin_bit_cast(unsigned, f);
  u = u + 0x7fffu + ((u >> 16) & 1u);
  return (unsigned short)(u >> 16);
}

__device__ __forceinline__ unsigned pk2(float a, float b) {
  return (unsigned)f2bf(a) | ((unsigned)f2bf(b) << 16);
}

__device__ __forceinline__ void gload16(const void* g, void* l) {
  __builtin_amdgcn_global_load_lds(
      (const __attribute__((address_space(1))) unsigned int*)g,
      (__attribute__((address_space(3))) unsigned int*)l, 16, 0, 0);
}

__device__ __forceinline__ void store_out(float* p, float v) { *p = v; }
__device__ __forceinline__ void store_out(unsigned short* p, float v) { *p = f2bf(v); }

// ---------------- fp32 -> bf16 convert (vectorized) ----------------
__global__ __launch_bounds__(256) void convert_f2b(const float* __restrict__ x,
                                                   unsigned short* __restrict__ y,
                                                   int n4) {
  int i = blockIdx.x * 256 + threadIdx.x;
  if (i >= n4) return;
  float4v v = ((const float4v*)x)[i];
  ushort4v u;
  u[0] = f2bf(v[0]); u[1] = f2bf(v[1]); u[2] = f2bf(v[2]); u[3] = f2bf(v[3]);
  ((ushort4v*)y)[i] = u;
}

// ---------------- W [K][N] fp32 -> Wt [N][K] bf16 ----------------
__global__ __launch_bounds__(256) void transpose_w(const float* __restrict__ W,
                                                   unsigned short* __restrict__ Wt) {
  __shared__ float tile[32][33];
  int bx = blockIdx.x * 32;
  int by = blockIdx.y * 32;
  int tx = threadIdx.x & 31;
  int ty = threadIdx.x >> 5;
#pragma unroll
  for (int j = 0; j < 32; j += 8)
    tile[ty + j][tx] = W[(size_t)(by + ty + j) * 1024 + bx + tx];
  __syncthreads();
#pragma unroll
  for (int j = 0; j < 32; j += 8)
    Wt[(size_t)(bx + ty + j) * 1024 + by + tx] = f2bf(tile[tx][ty + j]);
}

// ---------------- V [8192][1024] bf16 -> Vt [64*bh][2048] bf16 ----------------
__global__ __launch_bounds__(256) void transpose_v(const unsigned short* __restrict__ V,
                                                   unsigned short* __restrict__ Vt) {
  __shared__ unsigned short tile[64][66];
  int bi = blockIdx.x;
  int sb = bi & 31, hd = (bi >> 5) & 15, b = bi >> 9;
  const size_t inr0 = (size_t)b * 2048 + sb * 64;
  int r = threadIdx.x >> 3, c = threadIdx.x & 7;
#pragma unroll
  for (int i = 0; i < 2; ++i) {
    int row = r + 32 * i;
    ushort8 v = *(const ushort8*)&V[(inr0 + row) * 1024 + hd * 64 + c * 8];
#pragma unroll
    for (int j = 0; j < 8; ++j) tile[row][c * 8 + j] = v[j];
  }
  __syncthreads();
  const size_t outr0 = (size_t)(b * 16 + hd) * 64;
#pragma unroll
  for (int i = 0; i < 2; ++i) {
    int d = r + 32 * i;
    ushort8 v;
#pragma unroll
    for (int j = 0; j < 8; ++j) v[j] = tile[c * 8 + j][d];
    *(ushort8*)&Vt[(outr0 + d) * 2048 + sb * 64 + c * 8] = v;
  }
}

// ---------------- GEMM: C[M,N] = (A[M,K] * Bt[N,K]^T + bias) * scale ----------------
template <typename OT>
__global__ __launch_bounds__(256) void gemm_bt(const unsigned short* __restrict__ A,
                                               const unsigned short* __restrict__ Bt,
                                               const float* __restrict__ bias,
                                               OT* __restrict__ C, int M, int N, int K,
                                               float scale) {
  __shared__ __align__(16) unsigned short As[128 * 32];
  __shared__ __align__(16) unsigned short Bs[128 * 32];
  const int t = threadIdx.x;
  const int nb = N >> 7;
  const int bm = blockIdx.x / nb, bn = blockIdx.x % nb;
  const int lane = t & 63, wid = t >> 6;
  const int wr = wid >> 1, wc = wid & 1;
  const int lr = lane & 15, lg = lane >> 4;
  f32x4 acc[4][4] = {};
  const size_t baseA = (size_t)(bm * 128) * K;
  const size_t baseB = (size_t)(bn * 128) * K;
  const int c0 = t, c1 = t + 256;
  const int rA0 = c0 >> 2, kA0 = (c0 & 3) * 8;
  const int rA1 = c1 >> 2, kA1 = (c1 & 3) * 8;
  for (int ks = 0; ks < K; ks += 32) {
    __syncthreads();
    gload16(&A[baseA + (size_t)rA0 * K + ks + kA0], &As[c0 * 8]);
    gload16(&A[baseA + (size_t)rA1 * K + ks + kA1], &As[c1 * 8]);
    gload16(&Bt[baseB + (size_t)rA0 * K + ks + kA0], &Bs[c0 * 8]);
    gload16(&Bt[baseB + (size_t)rA1 * K + ks + kA1], &Bs[c1 * 8]);
    __syncthreads();
    bf16x8 a[4], b[4];
#pragma unroll
    for (int m = 0; m < 4; ++m)
      a[m] = *(const bf16x8*)&As[(wr * 64 + 16 * m + lr) * 32 + lg * 8];
#pragma unroll
    for (int n = 0; n < 4; ++n)
      b[n] = *(const bf16x8*)&Bs[(wc * 64 + 16 * n + lr) * 32 + lg * 8];
#pragma unroll
    for (int m = 0; m < 4; ++m)
#pragma unroll
      for (int n = 0; n < 4; ++n)
        acc[m][n] = __builtin_amdgcn_mfma_f32_16x16x32_bf16(a[m], b[n], acc[m][n], 0, 0, 0);
  }
  const int rowb = bm * 128 + wr * 64;
  const int colb = bn * 128 + wc * 64;
#pragma unroll
  for (int n = 0; n < 4; ++n) {
    int col = colb + 16 * n + lr;
    float bv = bias[col];
#pragma unroll
    for (int m = 0; m < 4; ++m) {
      int row0 = rowb + 16 * m + 4 * lg;
#pragma unroll
      for (int r = 0; r < 4; ++r) {
        float v = (acc[m][n][r] + bv) * scale;
        store_out(&C[(size_t)(row0 + r) * N + col], v);
      }
    }
  }
}

// ---------------- Flash attention (swapped-operand, P in registers) ----------------
// grid = 2048: bid = b*512 + h*32 + qb. 2 waves x 32 q-rows, KVBLK=64, dbuf.
// S^T = mfma(K,Q): lane holds S[key=16n+4lg+r][q=qb0+16m+lr]. Softmax in-lane +
// 2 shfl. PV k-slot permutation key(kk,lg,j)=32kk+16(j>>2)+4lg+(j&3) makes the
// P-fragment lane-local (zero shuffles); V^T consumed from swizzled LDS.
__global__ __launch_bounds__(128, 2) void attn_kernel(
    const unsigned short* __restrict__ Q, const unsigned short* __restrict__ K,
    const unsigned short* __restrict__ V, const int* __restrict__ mask,
    unsigned short* __restrict__ ctx) {
  __shared__ __align__(16) unsigned short Qs[64 * 64];
  __shared__ __align__(16) unsigned short Ks[2][64 * 64];
  __shared__ __align__(16) unsigned short Vs[2][64 * 64];
  __shared__ int s_any[2];
  const int bid = blockIdx.x;
  const int qb = bid & 31, h = (bid >> 5) & 15, b = bid >> 9;
  const int t = threadIdx.x;
  const int lane = t & 63, wid = t >> 6;
  const int lr = lane & 15, lg = lane >> 4;
  const size_t rowQ0 = (size_t)(b * 2048 + qb * 64);
  const int hcol = h * 64;
  const size_t vrow0 = (size_t)((b * 16 + h) * 64) * 2048;

  // per-thread staging bases (pre-swizzled global source, linear LDS dest)
  size_t ksrc[4], vsrc[4];
  int ldso[4];
#pragma unroll
  for (int i = 0; i < 4; ++i) {
    int ci = t + 128 * i;
    int row = ci >> 3, pos = ci & 7;
    ksrc[i] = (size_t)(b * 2048 + row) * 1024 + hcol + ((pos ^ (row & 7)) << 3);
    vsrc[i] = vrow0 + (size_t)row * 2048 + ((pos ^ ((row >> 1) & 7)) << 3);
    ldso[i] = ci * 8;
  }
  // stage Q tile [64 q][64 d]
#pragma unroll
  for (int i = 0; i < 4; ++i) {
    int ci = t + 128 * i;
    int row = ci >> 3, pos = ci & 7;
    gload16(&Q[(rowQ0 + row) * 1024 + hcol + ((pos ^ (row & 7)) << 3)], &Qs[ci * 8]);
  }
  // stage kb=0
#pragma unroll
  for (int i = 0; i < 4; ++i) gload16(&K[ksrc[i]], &Ks[0][ldso[i]]);
#pragma unroll
  for (int i = 0; i < 4; ++i) gload16(&V[vsrc[i]], &Vs[0][ldso[i]]);

  // block-wide mask scan
  int bad = 0;
  const int* mb = mask + b * 2048;
#pragma unroll
  for (int i = 0; i < 4; ++i) {
    int4 mv = *(const int4*)&mb[t * 16 + i * 4];
    bad |= (mv.x == 0) | (mv.y == 0) | (mv.z == 0) | (mv.w == 0);
  }
  unsigned long long bb = __ballot(bad);
  __syncthreads();  // Q/K0/V0 staged
  if (lane == 0) s_any[wid] = (bb != 0ULL);
  // hoist Q fragments: aq[m][kd] covers d = 32*kd + 8*lg + j for q = qb0+16m+lr
  bf16x8 aq[2][2];
#pragma unroll
  for (int m = 0; m < 2; ++m)
#pragma unroll
    for (int kd = 0; kd < 2; ++kd) {
      int row = wid * 32 + 16 * m + lr;
      int ch = (4 * kd + lg) ^ (lr & 7);
      aq[m][kd] = *(const bf16x8*)&Qs[row * 64 + ch * 8];
    }
  __syncthreads();  // s_any visible
  const bool anymask = (s_any[0] | s_any[1]) != 0;

  float m_run[2] = {-1e30f, -1e30f};
  float l_run[2] = {0.f, 0.f};
  f32x4 o[2][4] = {};
  const f32x4 zero4 = {0.f, 0.f, 0.f, 0.f};
  const int ch0 = (lg ^ (lr & 7)) * 8;
  const int ch1 = ((4 + lg) ^ (lr & 7)) * 8;
  const int sw = lr >> 1;

  for (int kb = 0; kb < 32; ++kb) {
    const int bi = kb & 1;
    // issue next-tile stage first (lands before end-of-iter barrier)
    if (kb + 1 < 32) {
      const size_t ko = (size_t)(kb + 1) * 64 * 1024;
      const size_t vo = (size_t)(kb + 1) * 64;
#pragma unroll
      for (int i = 0; i < 4; ++i) gload16(&K[ksrc[i] + ko], &Ks[bi ^ 1][ldso[i]]);
#pragma unroll
      for (int i = 0; i < 4; ++i) gload16(&V[vsrc[i] + vo], &Vs[bi ^ 1][ldso[i]]);
    }
    // ---- S^T = K Q^T : s[m][n][r] = S[key=16n+4lg+r][q] (scaled by log2e) ----
    const unsigned short* Kb_ = &Ks[bi][0];
    f32x4 s[2][4];
#pragma unroll
    for (int n = 0; n < 4; ++n) {
      bf16x8 k0 = *(const bf16x8*)&Kb_[(16 * n + lr) * 64 + ch0];
      bf16x8 k1 = *(const bf16x8*)&Kb_[(16 * n + lr) * 64 + ch1];
#pragma unroll
      for (int m = 0; m < 2; ++m) {
        f32x4 tmp = __builtin_amdgcn_mfma_f32_16x16x32_bf16(k0, aq[m][0], zero4, 0, 0, 0);
        s[m][n] = __builtin_amdgcn_mfma_f32_16x16x32_bf16(k1, aq[m][1], tmp, 0, 0, 0);
      }
    }
    if (anymask) {
      const int* mrow = mb + kb * 64;
#pragma unroll
      for (int n = 0; n < 4; ++n) {
        int4 mv = *(const int4*)&mrow[16 * n + 4 * lg];
        int mm[4] = {mv.x, mv.y, mv.z, mv.w};
#pragma unroll
        for (int r = 0; r < 4; ++r)
          if (mm[r] == 0) { s[0][n][r] = MASKED_VAL; s[1][n][r] = MASKED_VAL; }
      }
    }
    // ---- online softmax (base-2), per q-row = lane column ----
#pragma unroll
    for (int m = 0; m < 2; ++m) {
      float mx = fmaxf(fmaxf(s[m][0][0], s[m][0][1]), fmaxf(s[m][0][2], s[m][0][3]));
#pragma unroll
      for (int n = 1; n < 4; ++n) {
        mx = fmaxf(mx, fmaxf(fmaxf(s[m][n][0], s[m][n][1]), fmaxf(s[m][n][2], s[m][n][3])));
      }
      mx = fmaxf(mx, __shfl_xor(mx, 16));
      mx = fmaxf(mx, __shfl_xor(mx, 32));
      float mnew = fmaxf(m_run[m], mx);
      float corr = exp2f(m_run[m] - mnew);
      float rs = 0.f;
#pragma unroll
      for (int n = 0; n < 4; ++n)
#pragma unroll
        for (int r = 0; r < 4; ++r) {
          float p = exp2f(s[m][n][r] - mnew);
          s[m][n][r] = p;
          rs += p;
        }
      rs += __shfl_xor(rs, 16);
      rs += __shfl_xor(rs, 32);
      m_run[m] = mnew;
      l_run[m] = l_run[m] * corr + rs;
#pragma unroll
      for (int dn = 0; dn < 4; ++dn) o[m][dn] *= corr;
    }
    // ---- pack P to bf16 (lane-local) ----
    unsigned w[2][4][2];
#pragma unroll
    for (int m = 0; m < 2; ++m)
#pragma unroll
      for (int n = 0; n < 4; ++n) {
        w[m][n][0] = pk2(s[m][n][0], s[m][n][1]);
        w[m][n][1] = pk2(s[m][n][2], s[m][n][3]);
      }
    // ---- O^T += V^T P^T with permuted k-slots ----
    const unsigned short* Vb_ = &Vs[bi][0];
#pragma unroll
    for (int kk = 0; kk < 2; ++kk) {
      bf16x8 pf[2];
#pragma unroll
      for (int m = 0; m < 2; ++m) {
        uint4v u;
        u[0] = w[m][2 * kk][0];
        u[1] = w[m][2 * kk][1];
        u[2] = w[m][2 * kk + 1][0];
        u[3] = w[m][2 * kk + 1][1];
        pf[m] = __builtin_bit_cast(bf16x8, u);
      }
      const int p0 = (4 * kk + (lg >> 1)) ^ sw;
      const int base0 = lr * 64 + p0 * 8 + (lg & 1) * 4;
      const int base1 = lr * 64 + (p0 ^ 2) * 8 + (lg & 1) * 4;
#pragma unroll
      for (int dn = 0; dn < 4; ++dn) {
        bf16x4 v0 = *(const bf16x4*)&Vb_[base0 + dn * 1024];
        bf16x4 v1 = *(const bf16x4*)&Vb_[base1 + dn * 1024];
        bf16x8 vb = __builtin_shufflevector(v0, v1, 0, 1, 2, 3, 4, 5, 6, 7);
#pragma unroll
        for (int m = 0; m < 2; ++m)
          o[m][dn] = __builtin_amdgcn_mfma_f32_16x16x32_bf16(vb, pf[m], o[m][dn], 0, 0, 0);
      }
    }
    __syncthreads();  // drains next-tile stage; all reads of buf bi done
  }
  // ---- epilogue: o holds O^T[d=16dn+4lg+r][q=qb0+16m+lr] ----
#pragma unroll
  for (int m = 0; m < 2; ++m) {
    float inv = 1.f / l_run[m];
    size_t q = rowQ0 + wid * 32 + 16 * m + lr;
#pragma unroll
    for (int dn = 0; dn < 4; ++dn) {
      ushort4v u;
#pragma unroll
      for (int r = 0; r < 4; ++r) u[r] = f2bf(o[m][dn][r] * inv);
      *(ushort4v*)&ctx[q * 1024 + hcol + 16 * dn + 4 * lg] = u;
    }
  }
}

extern "C" void kernel_launch(void* const* d_in, const int* in_sizes, int n_in,
                              void* d_out, int out_size, void* d_ws, size_t ws_size,
                              hipStream_t stream) {
  const float* srcQ = (const float*)d_in[0];
  const float* srcK = (const float*)d_in[1];
  const float* srcV = (const float*)d_in[2];
  const int*   mask = (const int*)d_in[3];
  const float* Wq = (const float*)d_in[4];
  const float* bq = (const float*)d_in[5];
  const float* Wk = (const float*)d_in[6];
  const float* bk = (const float*)d_in[7];
  const float* Wv = (const float*)d_in[8];
  const float* bv = (const float*)d_in[9];
  const float* Wo = (const float*)d_in[10];
  const float* bo = (const float*)d_in[11];
  float* out = (float*)d_out;

  const int M = 8192, N = 1024, Kd = 1024;
  char* ws = (char*)d_ws;
  unsigned short* Xb  = (unsigned short*)(ws);                       // srcX bf16, later Vt
  unsigned short* Qb  = (unsigned short*)(ws + (size_t)(16 << 20));
  unsigned short* Kb  = (unsigned short*)(ws + (size_t)(32 << 20));
  unsigned short* Vb  = (unsigned short*)(ws + (size_t)(48 << 20));  // V gemm out, later ctx
  unsigned short* Wt  = (unsigned short*)(ws + (size_t)(64 << 20));  // 4 x 2 MiB
  unsigned short* VtG = Xb;
  unsigned short* ctx = Vb;

  dim3 tb(256);
  dim3 tg(32, 32);
  transpose_w<<<tg, tb, 0, stream>>>(Wq, Wt + 0 * (1 << 20));
  transpose_w<<<tg, tb, 0, stream>>>(Wk, Wt + 1 * (1 << 20));
  transpose_w<<<tg, tb, 0, stream>>>(Wv, Wt + 2 * (1 << 20));
  transpose_w<<<tg, tb, 0, stream>>>(Wo, Wt + 3 * (1 << 20));

  const int n4 = M * N / 4;
  const int gemm_grid = (M / 128) * (N / 128);

  convert_f2b<<<n4 / 256, 256, 0, stream>>>(srcQ, Xb, n4);
  gemm_bt<unsigned short><<<gemm_grid, 256, 0, stream>>>(Xb, Wt + 0 * (1 << 20), bq, Qb, M, N, Kd, LOG2E);
  convert_f2b<<<n4 / 256, 256, 0, stream>>>(srcK, Xb, n4);
  gemm_bt<unsigned short><<<gemm_grid, 256, 0, stream>>>(Xb, Wt + 1 * (1 << 20), bk, Kb, M, N, Kd, 1.0f);
  convert_f2b<<<n4 / 256, 256, 0, stream>>>(srcV, Xb, n4);
  gemm_bt<unsigned short><<<gemm_grid, 256, 0, stream>>>(Xb, Wt + 2 * (1 << 20), bv, Vb, M, N, Kd, 1.0f);

  transpose_v<<<2048, 256, 0, stream>>>(Vb, VtG);  // Xb's srcV copy is dead now

  attn_kernel<<<2048, 128, 0, stream>>>(Qb, Kb, VtG, mask, ctx);

  gemm_bt<float><<<gemm_grid, 256, 0, stream>>>(ctx, Wt + 3 * (1 << 20), bo, out, M, N, Kd, 1.0f);
}

// Round 4
// 262.449 us; speedup vs baseline: 2.3567x; 1.5830x over previous
//
#include <hip/hip_runtime.h>

typedef short bf16x8 __attribute__((ext_vector_type(8)));
typedef short bf16x4 __attribute__((ext_vector_type(4)));
typedef float f32x4 __attribute__((ext_vector_type(4)));
typedef unsigned short ushort8 __attribute__((ext_vector_type(8)));
typedef unsigned short ushort4v __attribute__((ext_vector_type(4)));
typedef unsigned int uint4v __attribute__((ext_vector_type(4)));
typedef float float4v __attribute__((ext_vector_type(4)));

#define LOG2E 1.4426950408889634f
#define MASKED_VAL -14426.950408889634f /* -10000 * log2(e) */
#define DEFER_THR 8.0f

__device__ __forceinline__ unsigned short f2bf(float f) {
  unsigned u = __builtin_bit_cast(unsigned, f);
  u = u + 0x7fffu + ((u >> 16) & 1u);
  return (unsigned short)(u >> 16);
}

// hardware packed f32->bf16 (RNE)
__device__ __forceinline__ unsigned pk2(float a, float b) {
  unsigned r;
  asm("v_cvt_pk_bf16_f32 %0, %1, %2" : "=v"(r) : "v"(a), "v"(b));
  return r;
}

// guaranteed single-instruction exp2
__device__ __forceinline__ float exp2a(float x) {
  float r;
  asm("v_exp_f32 %0, %1" : "=v"(r) : "v"(x));
  return r;
}

__device__ __forceinline__ void gload16(const void* g, void* l) {
  __builtin_amdgcn_global_load_lds(
      (const __attribute__((address_space(1))) unsigned int*)g,
      (__attribute__((address_space(3))) unsigned int*)l, 16, 0, 0);
}

__device__ __forceinline__ void store_out(float* p, float v) { *p = v; }
__device__ __forceinline__ void store_out(unsigned short* p, float v) { *p = f2bf(v); }

// ---------------- fp32 -> bf16 convert (vectorized) ----------------
__global__ __launch_bounds__(256) void convert_f2b(const float* __restrict__ x,
                                                   unsigned short* __restrict__ y,
                                                   int n4) {
  int i = blockIdx.x * 256 + threadIdx.x;
  if (i >= n4) return;
  float4v v = ((const float4v*)x)[i];
  ushort4v u;
  u[0] = f2bf(v[0]); u[1] = f2bf(v[1]); u[2] = f2bf(v[2]); u[3] = f2bf(v[3]);
  ((ushort4v*)y)[i] = u;
}

// ---------------- W [K][N] fp32 -> Wt [N][K] bf16 ----------------
__global__ __launch_bounds__(256) void transpose_w(const float* __restrict__ W,
                                                   unsigned short* __restrict__ Wt) {
  __shared__ float tile[32][33];
  int bx = blockIdx.x * 32;
  int by = blockIdx.y * 32;
  int tx = threadIdx.x & 31;
  int ty = threadIdx.x >> 5;
#pragma unroll
  for (int j = 0; j < 32; j += 8)
    tile[ty + j][tx] = W[(size_t)(by + ty + j) * 1024 + bx + tx];
  __syncthreads();
#pragma unroll
  for (int j = 0; j < 32; j += 8)
    Wt[(size_t)(bx + ty + j) * 1024 + by + tx] = f2bf(tile[tx][ty + j]);
}

// ---------------- V [8192][1024] bf16 -> Vt [64*bh][2048] bf16 ----------------
__global__ __launch_bounds__(256) void transpose_v(const unsigned short* __restrict__ V,
                                                   unsigned short* __restrict__ Vt) {
  __shared__ unsigned short tile[64][66];
  int bi = blockIdx.x;
  int sb = bi & 31, hd = (bi >> 5) & 15, b = bi >> 9;
  const size_t inr0 = (size_t)b * 2048 + sb * 64;
  int r = threadIdx.x >> 3, c = threadIdx.x & 7;
#pragma unroll
  for (int i = 0; i < 2; ++i) {
    int row = r + 32 * i;
    ushort8 v = *(const ushort8*)&V[(inr0 + row) * 1024 + hd * 64 + c * 8];
#pragma unroll
    for (int j = 0; j < 8; ++j) tile[row][c * 8 + j] = v[j];
  }
  __syncthreads();
  const size_t outr0 = (size_t)(b * 16 + hd) * 64;
#pragma unroll
  for (int i = 0; i < 2; ++i) {
    int d = r + 32 * i;
    ushort8 v;
#pragma unroll
    for (int j = 0; j < 8; ++j) v[j] = tile[c * 8 + j][d];
    *(ushort8*)&Vt[(outr0 + d) * 2048 + sb * 64 + c * 8] = v;
  }
}

// ---------------- GEMM: C[M,N] = (A[M,K] * Bt[N,K]^T + bias) * scale ----------------
template <typename OT>
__global__ __launch_bounds__(256) void gemm_bt(const unsigned short* __restrict__ A,
                                               const unsigned short* __restrict__ Bt,
                                               const float* __restrict__ bias,
                                               OT* __restrict__ C, int M, int N, int K,
                                               float scale) {
  __shared__ __align__(16) unsigned short As[128 * 32];
  __shared__ __align__(16) unsigned short Bs[128 * 32];
  const int t = threadIdx.x;
  const int nb = N >> 7;
  const int bm = blockIdx.x / nb, bn = blockIdx.x % nb;
  const int lane = t & 63, wid = t >> 6;
  const int wr = wid >> 1, wc = wid & 1;
  const int lr = lane & 15, lg = lane >> 4;
  f32x4 acc[4][4] = {};
  const size_t baseA = (size_t)(bm * 128) * K;
  const size_t baseB = (size_t)(bn * 128) * K;
  const int c0 = t, c1 = t + 256;
  const int rA0 = c0 >> 2, kA0 = (c0 & 3) * 8;
  const int rA1 = c1 >> 2, kA1 = (c1 & 3) * 8;
  for (int ks = 0; ks < K; ks += 32) {
    __syncthreads();
    gload16(&A[baseA + (size_t)rA0 * K + ks + kA0], &As[c0 * 8]);
    gload16(&A[baseA + (size_t)rA1 * K + ks + kA1], &As[c1 * 8]);
    gload16(&Bt[baseB + (size_t)rA0 * K + ks + kA0], &Bs[c0 * 8]);
    gload16(&Bt[baseB + (size_t)rA1 * K + ks + kA1], &Bs[c1 * 8]);
    __syncthreads();
    bf16x8 a[4], b[4];
#pragma unroll
    for (int m = 0; m < 4; ++m)
      a[m] = *(const bf16x8*)&As[(wr * 64 + 16 * m + lr) * 32 + lg * 8];
#pragma unroll
    for (int n = 0; n < 4; ++n)
      b[n] = *(const bf16x8*)&Bs[(wc * 64 + 16 * n + lr) * 32 + lg * 8];
#pragma unroll
    for (int m = 0; m < 4; ++m)
#pragma unroll
      for (int n = 0; n < 4; ++n)
        acc[m][n] = __builtin_amdgcn_mfma_f32_16x16x32_bf16(a[m], b[n], acc[m][n], 0, 0, 0);
  }
  const int rowb = bm * 128 + wr * 64;
  const int colb = bn * 128 + wc * 64;
#pragma unroll
  for (int n = 0; n < 4; ++n) {
    int col = colb + 16 * n + lr;
    float bv = bias[col];
#pragma unroll
    for (int m = 0; m < 4; ++m) {
      int row0 = rowb + 16 * m + 4 * lg;
#pragma unroll
      for (int r = 0; r < 4; ++r) {
        float v = (acc[m][n][r] + bv) * scale;
        store_out(&C[(size_t)(row0 + r) * N + col], v);
      }
    }
  }
}

// ---------------- Flash attention (swapped-operand, P in registers) ----------------
// grid = 1024: bid = b*256 + h*16 + qb. 4 waves x 32 q-rows (128/block), KVBLK=64.
// LDS pool 32KB: [K0|K1|V0|V1]; Q staged through K0+K1 region pre-loop.
// Softmax: defer-max (THR=8) with -m_run folded into QK C-seed; l via ones-MFMA.
__global__ __launch_bounds__(256, 4) void attn_kernel(
    const unsigned short* __restrict__ Q, const unsigned short* __restrict__ K,
    const unsigned short* __restrict__ V, const int* __restrict__ mask,
    unsigned short* __restrict__ ctx) {
  __shared__ __align__(16) unsigned short pool[16384];  // 32 KB
  __shared__ int s_any[4];
  unsigned short* Kbuf0 = pool;
  unsigned short* Kbuf1 = pool + 4096;
  unsigned short* Vbuf0 = pool + 8192;
  unsigned short* Vbuf1 = pool + 12288;
  const int bid = blockIdx.x;
  const int qb = bid & 15, h = (bid >> 4) & 15, b = bid >> 8;
  const int t = threadIdx.x;
  const int lane = t & 63, wid = t >> 6;
  const int lr = lane & 15, lg = lane >> 4;
  const size_t rowQ0 = (size_t)(b * 2048 + qb * 128);
  const int hcol = h * 64;
  const size_t vrow0 = (size_t)((b * 16 + h) * 64) * 2048;

  // per-thread K/V staging bases (pre-swizzled global source, linear LDS dest)
  size_t ksrc[2], vsrc[2];
  int ldso[2];
#pragma unroll
  for (int i = 0; i < 2; ++i) {
    int ci = t + 256 * i;  // 0..511
    int row = ci >> 3, pos = ci & 7;
    ksrc[i] = (size_t)(b * 2048 + row) * 1024 + hcol + ((pos ^ (row & 7)) << 3);
    vsrc[i] = vrow0 + (size_t)row * 2048 + ((pos ^ ((row >> 1) & 7)) << 3);
    ldso[i] = ci * 8;
  }
  // stage Q tile [128 q][64 d] into pool[0..8191] (K region, pre-loop reuse)
#pragma unroll
  for (int i = 0; i < 4; ++i) {
    int ci = t + 256 * i;  // 0..1023
    int row = ci >> 3, pos = ci & 7;
    gload16(&Q[(rowQ0 + row) * 1024 + hcol + ((pos ^ (row & 7)) << 3)], &pool[ci * 8]);
  }
  // block-wide mask scan (8 ints per thread)
  int bad = 0;
  const int* mb = mask + b * 2048;
#pragma unroll
  for (int i = 0; i < 2; ++i) {
    int4 mv = *(const int4*)&mb[t * 8 + i * 4];
    bad |= (mv.x == 0) | (mv.y == 0) | (mv.z == 0) | (mv.w == 0);
  }
  unsigned long long bb = __ballot(bad);
  if (lane == 0) s_any[wid] = (bb != 0ULL);
  __syncthreads();  // Q staged + s_any visible
  // hoist Q fragments: aq[m][kd], q-row = wid*32 + 16m + lr
  bf16x8 aq[2][2];
#pragma unroll
  for (int m = 0; m < 2; ++m)
#pragma unroll
    for (int kd = 0; kd < 2; ++kd) {
      int row = wid * 32 + 16 * m + lr;
      int ch = (4 * kd + lg) ^ (lr & 7);
      aq[m][kd] = *(const bf16x8*)&pool[row * 64 + ch * 8];
    }
  const bool anymask = (s_any[0] | s_any[1] | s_any[2] | s_any[3]) != 0;
  __syncthreads();  // all Q-frag reads done -> pool reusable
  // stage kb=0
#pragma unroll
  for (int i = 0; i < 2; ++i) gload16(&K[ksrc[i]], &Kbuf0[ldso[i]]);
#pragma unroll
  for (int i = 0; i < 2; ++i) gload16(&V[vsrc[i]], &Vbuf0[ldso[i]]);
  __syncthreads();  // K0/V0 ready

  float m_run[2] = {0.f, 0.f};
  f32x4 o[2][4] = {};
  f32x4 ol[2] = {};
  const short oneb = 0x3F80;
  const bf16x8 ones8 = {oneb, oneb, oneb, oneb, oneb, oneb, oneb, oneb};
  const int ch0 = (lg ^ (lr & 7)) * 8;
  const int ch1 = ((4 + lg) ^ (lr & 7)) * 8;
  const int sw = lr >> 1;

  for (int kb = 0; kb < 32; ++kb) {
    const int bi = kb & 1;
    const unsigned short* Kb_ = bi ? Kbuf1 : Kbuf0;
    const unsigned short* Vb_ = bi ? Vbuf1 : Vbuf0;
    unsigned short* Kn_ = bi ? Kbuf0 : Kbuf1;
    unsigned short* Vn_ = bi ? Vbuf0 : Vbuf1;
    // issue next-tile stage first (lands before end-of-iter barrier)
    if (kb + 1 < 32) {
      const size_t ko = (size_t)(kb + 1) * 64 * 1024;
      const size_t vo = (size_t)(kb + 1) * 64;
#pragma unroll
      for (int i = 0; i < 2; ++i) gload16(&K[ksrc[i] + ko], &Kn_[ldso[i]]);
#pragma unroll
      for (int i = 0; i < 2; ++i) gload16(&V[vsrc[i] + vo], &Vn_[ldso[i]]);
    }
    // ---- S^T = K Q^T, pre-shifted by -m_run via C-seed ----
    f32x4 s[2][4];
    const f32x4 c0m = {-m_run[0], -m_run[0], -m_run[0], -m_run[0]};
    const f32x4 c1m = {-m_run[1], -m_run[1], -m_run[1], -m_run[1]};
#pragma unroll
    for (int n = 0; n < 4; ++n) {
      bf16x8 k0 = *(const bf16x8*)&Kb_[(16 * n + lr) * 64 + ch0];
      bf16x8 k1 = *(const bf16x8*)&Kb_[(16 * n + lr) * 64 + ch1];
      f32x4 t0 = __builtin_amdgcn_mfma_f32_16x16x32_bf16(k0, aq[0][0], c0m, 0, 0, 0);
      s[0][n] = __builtin_amdgcn_mfma_f32_16x16x32_bf16(k1, aq[0][1], t0, 0, 0, 0);
      f32x4 t1 = __builtin_amdgcn_mfma_f32_16x16x32_bf16(k0, aq[1][0], c1m, 0, 0, 0);
      s[1][n] = __builtin_amdgcn_mfma_f32_16x16x32_bf16(k1, aq[1][1], t1, 0, 0, 0);
    }
    if (anymask) {
      const int* mrow = mb + kb * 64;
#pragma unroll
      for (int n = 0; n < 4; ++n) {
        int4 mv = *(const int4*)&mrow[16 * n + 4 * lg];
        int mm[4] = {mv.x, mv.y, mv.z, mv.w};
#pragma unroll
        for (int r = 0; r < 4; ++r)
          if (mm[r] == 0) {
            s[0][n][r] = MASKED_VAL - m_run[0];
            s[1][n][r] = MASKED_VAL - m_run[1];
          }
      }
    }
    // ---- deferred-max online softmax (base-2, shifted space) ----
#pragma unroll
    for (int m = 0; m < 2; ++m) {
      float a0 = fmaxf(fmaxf(s[m][0][0], s[m][0][1]), fmaxf(s[m][0][2], s[m][0][3]));
      float a1 = fmaxf(fmaxf(s[m][1][0], s[m][1][1]), fmaxf(s[m][1][2], s[m][1][3]));
      float a2 = fmaxf(fmaxf(s[m][2][0], s[m][2][1]), fmaxf(s[m][2][2], s[m][2][3]));
      float a3 = fmaxf(fmaxf(s[m][3][0], s[m][3][1]), fmaxf(s[m][3][2], s[m][3][3]));
      float pmax = fmaxf(fmaxf(a0, a1), fmaxf(a2, a3));
      if (__any(pmax > DEFER_THR)) {  // slow path: real max update + rescale
        float mx = fmaxf(pmax, __shfl_xor(pmax, 16));
        mx = fmaxf(mx, __shfl_xor(mx, 32));
        float corr = exp2a(-mx);
        m_run[m] += mx;
#pragma unroll
        for (int n = 0; n < 4; ++n)
#pragma unroll
          for (int r = 0; r < 4; ++r) s[m][n][r] -= mx;
#pragma unroll
        for (int dn = 0; dn < 4; ++dn) o[m][dn] *= corr;
        ol[m] *= corr;
      }
      // exp (fast path: no subtract needed, already shifted)
#pragma unroll
      for (int n = 0; n < 4; ++n)
#pragma unroll
        for (int r = 0; r < 4; ++r) s[m][n][r] = exp2a(s[m][n][r]);
    }
    // ---- O^T += V^T P^T (permuted k-slots); l via ones-MFMA ----
#pragma unroll
    for (int kk = 0; kk < 2; ++kk) {
      bf16x8 pf[2];
#pragma unroll
      for (int m = 0; m < 2; ++m) {
        uint4v u;
        u[0] = pk2(s[m][2 * kk][0], s[m][2 * kk][1]);
        u[1] = pk2(s[m][2 * kk][2], s[m][2 * kk][3]);
        u[2] = pk2(s[m][2 * kk + 1][0], s[m][2 * kk + 1][1]);
        u[3] = pk2(s[m][2 * kk + 1][2], s[m][2 * kk + 1][3]);
        pf[m] = __builtin_bit_cast(bf16x8, u);
      }
      ol[0] = __builtin_amdgcn_mfma_f32_16x16x32_bf16(ones8, pf[0], ol[0], 0, 0, 0);
      ol[1] = __builtin_amdgcn_mfma_f32_16x16x32_bf16(ones8, pf[1], ol[1], 0, 0, 0);
      const int p0 = (4 * kk + (lg >> 1)) ^ sw;
      const int base0 = lr * 64 + p0 * 8 + (lg & 1) * 4;
      const int base1 = lr * 64 + (p0 ^ 2) * 8 + (lg & 1) * 4;
#pragma unroll
      for (int dn = 0; dn < 4; ++dn) {
        bf16x4 v0 = *(const bf16x4*)&Vb_[base0 + dn * 1024];
        bf16x4 v1 = *(const bf16x4*)&Vb_[base1 + dn * 1024];
        bf16x8 vb = __builtin_shufflevector(v0, v1, 0, 1, 2, 3, 4, 5, 6, 7);
#pragma unroll
        for (int m = 0; m < 2; ++m)
          o[m][dn] = __builtin_amdgcn_mfma_f32_16x16x32_bf16(vb, pf[m], o[m][dn], 0, 0, 0);
      }
    }
    __syncthreads();  // drains next-tile stage; all reads of buf bi done
  }
  // ---- epilogue: o holds O^T[d=16dn+4lg+r][q]; l = ol[m][any r] ----
#pragma unroll
  for (int m = 0; m < 2; ++m) {
    float inv = 1.f / ol[m][0];
    size_t q = rowQ0 + wid * 32 + 16 * m + lr;
#pragma unroll
    for (int dn = 0; dn < 4; ++dn) {
      ushort4v u;
#pragma unroll
      for (int r = 0; r < 4; ++r) u[r] = f2bf(o[m][dn][r] * inv);
      *(ushort4v*)&ctx[q * 1024 + hcol + 16 * dn + 4 * lg] = u;
    }
  }
}

extern "C" void kernel_launch(void* const* d_in, const int* in_sizes, int n_in,
                              void* d_out, int out_size, void* d_ws, size_t ws_size,
                              hipStream_t stream) {
  const float* srcQ = (const float*)d_in[0];
  const float* srcK = (const float*)d_in[1];
  const float* srcV = (const float*)d_in[2];
  const int*   mask = (const int*)d_in[3];
  const float* Wq = (const float*)d_in[4];
  const float* bq = (const float*)d_in[5];
  const float* Wk = (const float*)d_in[6];
  const float* bk = (const float*)d_in[7];
  const float* Wv = (const float*)d_in[8];
  const float* bv = (const float*)d_in[9];
  const float* Wo = (const float*)d_in[10];
  const float* bo = (const float*)d_in[11];
  float* out = (float*)d_out;

  const int M = 8192, N = 1024, Kd = 1024;
  char* ws = (char*)d_ws;
  unsigned short* Xb  = (unsigned short*)(ws);                       // srcX bf16, later Vt
  unsigned short* Qb  = (unsigned short*)(ws + (size_t)(16 << 20));
  unsigned short* Kb  = (unsigned short*)(ws + (size_t)(32 << 20));
  unsigned short* Vb  = (unsigned short*)(ws + (size_t)(48 << 20));  // V gemm out, later ctx
  unsigned short* Wt  = (unsigned short*)(ws + (size_t)(64 << 20));  // 4 x 2 MiB
  unsigned short* VtG = Xb;
  unsigned short* ctx = Vb;

  dim3 tb(256);
  dim3 tg(32, 32);
  transpose_w<<<tg, tb, 0, stream>>>(Wq, Wt + 0 * (1 << 20));
  transpose_w<<<tg, tb, 0, stream>>>(Wk, Wt + 1 * (1 << 20));
  transpose_w<<<tg, tb, 0, stream>>>(Wv, Wt + 2 * (1 << 20));
  transpose_w<<<tg, tb, 0, stream>>>(Wo, Wt + 3 * (1 << 20));

  const int n4 = M * N / 4;
  const int gemm_grid = (M / 128) * (N / 128);

  convert_f2b<<<n4 / 256, 256, 0, stream>>>(srcQ, Xb, n4);
  gemm_bt<unsigned short><<<gemm_grid, 256, 0, stream>>>(Xb, Wt + 0 * (1 << 20), bq, Qb, M, N, Kd, LOG2E);
  convert_f2b<<<n4 / 256, 256, 0, stream>>>(srcK, Xb, n4);
  gemm_bt<unsigned short><<<gemm_grid, 256, 0, stream>>>(Xb, Wt + 1 * (1 << 20), bk, Kb, M, N, Kd, 1.0f);
  convert_f2b<<<n4 / 256, 256, 0, stream>>>(srcV, Xb, n4);
  gemm_bt<unsigned short><<<gemm_grid, 256, 0, stream>>>(Xb, Wt + 2 * (1 << 20), bv, Vb, M, N, Kd, 1.0f);

  transpose_v<<<2048, 256, 0, stream>>>(Vb, VtG);  // Xb's srcV copy is dead now

  attn_kernel<<<1024, 256, 0, stream>>>(Qb, Kb, VtG, mask, ctx);

  gemm_bt<float><<<gemm_grid, 256, 0, stream>>>(ctx, Wt + 3 * (1 << 20), bo, out, M, N, Kd, 1.0f);
}

// Round 5
// 245.826 us; speedup vs baseline: 2.5161x; 1.0676x over previous
//
#include <hip/hip_runtime.h>

typedef short bf16x8 __attribute__((ext_vector_type(8)));
typedef short bf16x4 __attribute__((ext_vector_type(4)));
typedef float f32x4 __attribute__((ext_vector_type(4)));
typedef unsigned short ushort8 __attribute__((ext_vector_type(8)));
typedef unsigned short ushort4v __attribute__((ext_vector_type(4)));
typedef unsigned int uint4v __attribute__((ext_vector_type(4)));
typedef float float4v __attribute__((ext_vector_type(4)));

#define LOG2E 1.4426950408889634f
#define MASKED_VAL -14426.950408889634f /* -10000 * log2(e) */
#define DEFER_THR 8.0f

__device__ __forceinline__ unsigned short f2bf(float f) {
  unsigned u = __builtin_bit_cast(unsigned, f);
  u = u + 0x7fffu + ((u >> 16) & 1u);
  return (unsigned short)(u >> 16);
}

// hardware packed f32->bf16 (RNE)
__device__ __forceinline__ unsigned pk2(float a, float b) {
  unsigned r;
  asm("v_cvt_pk_bf16_f32 %0, %1, %2" : "=v"(r) : "v"(a), "v"(b));
  return r;
}

// guaranteed single-instruction exp2
__device__ __forceinline__ float exp2a(float x) {
  float r;
  asm("v_exp_f32 %0, %1" : "=v"(r) : "v"(x));
  return r;
}

__device__ __forceinline__ void gload16(const void* g, void* l) {
  __builtin_amdgcn_global_load_lds(
      (const __attribute__((address_space(1))) unsigned int*)g,
      (__attribute__((address_space(3))) unsigned int*)l, 16, 0, 0);
}

__device__ __forceinline__ void store_out(float* p, float v) { *p = v; }
__device__ __forceinline__ void store_out(unsigned short* p, float v) { *p = f2bf(v); }

// ---------------- fp32 -> bf16 convert (vectorized) ----------------
__global__ __launch_bounds__(256) void convert_f2b(const float* __restrict__ x,
                                                   unsigned short* __restrict__ y,
                                                   int n4) {
  int i = blockIdx.x * 256 + threadIdx.x;
  if (i >= n4) return;
  float4v v = ((const float4v*)x)[i];
  ushort4v u;
  u[0] = f2bf(v[0]); u[1] = f2bf(v[1]); u[2] = f2bf(v[2]); u[3] = f2bf(v[3]);
  ((ushort4v*)y)[i] = u;
}

// ---------------- W [K][N] fp32 -> Wt [N][K] bf16 ----------------
__global__ __launch_bounds__(256) void transpose_w(const float* __restrict__ W,
                                                   unsigned short* __restrict__ Wt) {
  __shared__ float tile[32][33];
  int bx = blockIdx.x * 32;
  int by = blockIdx.y * 32;
  int tx = threadIdx.x & 31;
  int ty = threadIdx.x >> 5;
#pragma unroll
  for (int j = 0; j < 32; j += 8)
    tile[ty + j][tx] = W[(size_t)(by + ty + j) * 1024 + bx + tx];
  __syncthreads();
#pragma unroll
  for (int j = 0; j < 32; j += 8)
    Wt[(size_t)(bx + ty + j) * 1024 + by + tx] = f2bf(tile[tx][ty + j]);
}

// ---------------- GEMM: C[M,N] = (A[M,K] * Bt[N,K]^T + bias) * scale ----------------
// m97 structure + XCD-aware bm-slice swizzle. VT=true writes V^T layout
// Vt[(b*1024 + col)][s] (kills the separate transpose_v pass).
template <typename OT, bool VT>
__global__ __launch_bounds__(256) void gemm_bt(const unsigned short* __restrict__ A,
                                               const unsigned short* __restrict__ Bt,
                                               const float* __restrict__ bias,
                                               OT* __restrict__ C, int M, int N, int K,
                                               float scale) {
  __shared__ __align__(16) unsigned short As[128 * 32];
  __shared__ __align__(16) unsigned short Bs[128 * 32];
  const int t = threadIdx.x;
  const int nb = N >> 7;
  int bm, bn;
  if ((M >> 7) == 64 && nb == 8) {
    // XCD swizzle: xcd = bid&7 owns bm in [8*xcd, 8*xcd+8), bn-minor
    int x = blockIdx.x & 7, i = blockIdx.x >> 3;
    bm = (x << 3) + (i >> 3);
    bn = i & 7;
  } else {
    bm = blockIdx.x / nb;
    bn = blockIdx.x % nb;
  }
  const int lane = t & 63, wid = t >> 6;
  const int wr = wid >> 1, wc = wid & 1;
  const int lr = lane & 15, lg = lane >> 4;
  f32x4 acc[4][4] = {};
  const size_t baseA = (size_t)(bm * 128) * K;
  const size_t baseB = (size_t)(bn * 128) * K;
  const int c0 = t, c1 = t + 256;
  const int rA0 = c0 >> 2, kA0 = (c0 & 3) * 8;
  const int rA1 = c1 >> 2, kA1 = (c1 & 3) * 8;
  for (int ks = 0; ks < K; ks += 32) {
    __syncthreads();
    gload16(&A[baseA + (size_t)rA0 * K + ks + kA0], &As[c0 * 8]);
    gload16(&A[baseA + (size_t)rA1 * K + ks + kA1], &As[c1 * 8]);
    gload16(&Bt[baseB + (size_t)rA0 * K + ks + kA0], &Bs[c0 * 8]);
    gload16(&Bt[baseB + (size_t)rA1 * K + ks + kA1], &Bs[c1 * 8]);
    __syncthreads();
    bf16x8 a[4], b[4];
#pragma unroll
    for (int m = 0; m < 4; ++m)
      a[m] = *(const bf16x8*)&As[(wr * 64 + 16 * m + lr) * 32 + lg * 8];
#pragma unroll
    for (int n = 0; n < 4; ++n)
      b[n] = *(const bf16x8*)&Bs[(wc * 64 + 16 * n + lr) * 32 + lg * 8];
#pragma unroll
    for (int m = 0; m < 4; ++m)
#pragma unroll
      for (int n = 0; n < 4; ++n)
        acc[m][n] = __builtin_amdgcn_mfma_f32_16x16x32_bf16(a[m], b[n], acc[m][n], 0, 0, 0);
  }
  const int rowb = bm * 128 + wr * 64;
  const int colb = bn * 128 + wc * 64;
  if constexpr (VT) {
    // V^T epilogue: row = b*2048 + s; write Vt[(b*1024+col)*2048 + s]
    const int bidx = rowb >> 11;
    const int srow = rowb & 2047;
#pragma unroll
    for (int n = 0; n < 4; ++n) {
      int col = colb + 16 * n + lr;
      float bv = bias[col];
#pragma unroll
      for (int m = 0; m < 4; ++m) {
        int s0 = srow + 16 * m + 4 * lg;
        ushort4v u;
#pragma unroll
        for (int r = 0; r < 4; ++r) u[r] = f2bf((acc[m][n][r] + bv) * scale);
        *(ushort4v*)&C[((size_t)(bidx * 1024 + col)) * 2048 + s0] = u;
      }
    }
  } else {
#pragma unroll
    for (int n = 0; n < 4; ++n) {
      int col = colb + 16 * n + lr;
      float bv = bias[col];
#pragma unroll
      for (int m = 0; m < 4; ++m) {
        int row0 = rowb + 16 * m + 4 * lg;
#pragma unroll
        for (int r = 0; r < 4; ++r) {
          float v = (acc[m][n][r] + bv) * scale;
          store_out(&C[(size_t)(row0 + r) * N + col], v);
        }
      }
    }
  }
}

// ---------------- Flash attention (swapped-operand, P in registers) ----------------
// grid = 1024, XCD-swizzled: logical bid = (g&7)*128 + (g>>3) -> each XCD owns
// 8 contiguous (b,h) groups (K/V slices L2-resident per XCD).
// 4 waves x 32 q-rows (128/block), KVBLK=64. LDS 32KB: [K0|K1|V0|V1].
// Softmax: defer-max (THR=8, shared m_run) folded into QK C-seed; l via ones-MFMA.
__global__ __launch_bounds__(256, 4) void attn_kernel(
    const unsigned short* __restrict__ Q, const unsigned short* __restrict__ K,
    const unsigned short* __restrict__ V, const int* __restrict__ mask,
    unsigned short* __restrict__ ctx) {
  __shared__ __align__(16) unsigned short pool[16384];  // 32 KB
  __shared__ int s_any[4];
  unsigned short* Kbuf0 = pool;
  unsigned short* Kbuf1 = pool + 4096;
  unsigned short* Vbuf0 = pool + 8192;
  unsigned short* Vbuf1 = pool + 12288;
  const int g = blockIdx.x;
  const int bid = (g & 7) * 128 + (g >> 3);  // XCD-contiguous logical id
  const int qb = bid & 15, h = (bid >> 4) & 15, b = bid >> 8;
  const int t = threadIdx.x;
  const int lane = t & 63, wid = t >> 6;
  const int lr = lane & 15, lg = lane >> 4;
  const size_t rowQ0 = (size_t)(b * 2048 + qb * 128);
  const int hcol = h * 64;
  const size_t vrow0 = (size_t)((b * 16 + h) * 64) * 2048;

  // per-thread K/V staging bases (pre-swizzled global source, linear LDS dest)
  size_t ksrc[2], vsrc[2];
  int ldso[2];
#pragma unroll
  for (int i = 0; i < 2; ++i) {
    int ci = t + 256 * i;  // 0..511
    int row = ci >> 3, pos = ci & 7;
    ksrc[i] = (size_t)(b * 2048 + row) * 1024 + hcol + ((pos ^ (row & 7)) << 3);
    vsrc[i] = vrow0 + (size_t)row * 2048 + ((pos ^ ((row >> 1) & 7)) << 3);
    ldso[i] = ci * 8;
  }
  // stage Q tile [128 q][64 d] into pool[0..8191] (K region, pre-loop reuse)
#pragma unroll
  for (int i = 0; i < 4; ++i) {
    int ci = t + 256 * i;  // 0..1023
    int row = ci >> 3, pos = ci & 7;
    gload16(&Q[(rowQ0 + row) * 1024 + hcol + ((pos ^ (row & 7)) << 3)], &pool[ci * 8]);
  }
  // block-wide mask scan (8 ints per thread)
  int bad = 0;
  const int* mb = mask + b * 2048;
#pragma unroll
  for (int i = 0; i < 2; ++i) {
    int4 mv = *(const int4*)&mb[t * 8 + i * 4];
    bad |= (mv.x == 0) | (mv.y == 0) | (mv.z == 0) | (mv.w == 0);
  }
  unsigned long long bb = __ballot(bad);
  if (lane == 0) s_any[wid] = (bb != 0ULL);
  __syncthreads();  // Q staged + s_any visible
  // hoist Q fragments: aq[m][kd], q-row = wid*32 + 16m + lr
  bf16x8 aq[2][2];
#pragma unroll
  for (int m = 0; m < 2; ++m)
#pragma unroll
    for (int kd = 0; kd < 2; ++kd) {
      int row = wid * 32 + 16 * m + lr;
      int ch = (4 * kd + lg) ^ (lr & 7);
      aq[m][kd] = *(const bf16x8*)&pool[row * 64 + ch * 8];
    }
  const bool anymask = (s_any[0] | s_any[1] | s_any[2] | s_any[3]) != 0;
  __syncthreads();  // all Q-frag reads done -> pool reusable
  // stage kb=0
#pragma unroll
  for (int i = 0; i < 2; ++i) gload16(&K[ksrc[i]], &Kbuf0[ldso[i]]);
#pragma unroll
  for (int i = 0; i < 2; ++i) gload16(&V[vsrc[i]], &Vbuf0[ldso[i]]);
  __syncthreads();  // K0/V0 ready

  float m_run = 0.f;
  f32x4 o[2][4] = {};
  f32x4 ol[2] = {};
  const short oneb = 0x3F80;
  const bf16x8 ones8 = {oneb, oneb, oneb, oneb, oneb, oneb, oneb, oneb};
  const int ch0 = (lg ^ (lr & 7)) * 8;
  const int ch1 = ((4 + lg) ^ (lr & 7)) * 8;
  const int sw = lr >> 1;

  for (int kb = 0; kb < 32; ++kb) {
    const int bi = kb & 1;
    const unsigned short* Kb_ = bi ? Kbuf1 : Kbuf0;
    const unsigned short* Vb_ = bi ? Vbuf1 : Vbuf0;
    unsigned short* Kn_ = bi ? Kbuf0 : Kbuf1;
    unsigned short* Vn_ = bi ? Vbuf0 : Vbuf1;
    // issue next-tile stage first (lands before end-of-iter barrier)
    if (kb + 1 < 32) {
      const size_t ko = (size_t)(kb + 1) * 64 * 1024;
      const size_t vo = (size_t)(kb + 1) * 64;
#pragma unroll
      for (int i = 0; i < 2; ++i) gload16(&K[ksrc[i] + ko], &Kn_[ldso[i]]);
#pragma unroll
      for (int i = 0; i < 2; ++i) gload16(&V[vsrc[i] + vo], &Vn_[ldso[i]]);
    }
    // ---- S^T = K Q^T, pre-shifted by -m_run via C-seed ----
    f32x4 s[2][4];
    const f32x4 cm = {-m_run, -m_run, -m_run, -m_run};
#pragma unroll
    for (int n = 0; n < 4; ++n) {
      bf16x8 k0 = *(const bf16x8*)&Kb_[(16 * n + lr) * 64 + ch0];
      bf16x8 k1 = *(const bf16x8*)&Kb_[(16 * n + lr) * 64 + ch1];
      f32x4 t0 = __builtin_amdgcn_mfma_f32_16x16x32_bf16(k0, aq[0][0], cm, 0, 0, 0);
      s[0][n] = __builtin_amdgcn_mfma_f32_16x16x32_bf16(k1, aq[0][1], t0, 0, 0, 0);
      f32x4 t1 = __builtin_amdgcn_mfma_f32_16x16x32_bf16(k0, aq[1][0], cm, 0, 0, 0);
      s[1][n] = __builtin_amdgcn_mfma_f32_16x16x32_bf16(k1, aq[1][1], t1, 0, 0, 0);
    }
    if (anymask) {
      const int* mrow = mb + kb * 64;
#pragma unroll
      for (int n = 0; n < 4; ++n) {
        int4 mv = *(const int4*)&mrow[16 * n + 4 * lg];
        int mm[4] = {mv.x, mv.y, mv.z, mv.w};
#pragma unroll
        for (int r = 0; r < 4; ++r)
          if (mm[r] == 0) {
            s[0][n][r] = MASKED_VAL - m_run;
            s[1][n][r] = MASKED_VAL - m_run;
          }
      }
    }
    // ---- deferred-max online softmax (base-2, shifted space, shared m_run) ----
    {
      float pmax = s[0][0][0];
#pragma unroll
      for (int m = 0; m < 2; ++m)
#pragma unroll
        for (int n = 0; n < 4; ++n) {
          float a = fmaxf(fmaxf(s[m][n][0], s[m][n][1]), fmaxf(s[m][n][2], s[m][n][3]));
          pmax = fmaxf(pmax, a);
        }
      if (__any(pmax > DEFER_THR)) {  // rare slow path: shift + rescale
        float mx = fmaxf(pmax, __shfl_xor(pmax, 16));
        mx = fmaxf(mx, __shfl_xor(mx, 32));
        float corr = exp2a(-mx);
        m_run += mx;
#pragma unroll
        for (int m = 0; m < 2; ++m)
#pragma unroll
          for (int n = 0; n < 4; ++n)
#pragma unroll
            for (int r = 0; r < 4; ++r) s[m][n][r] -= mx;
#pragma unroll
        for (int m = 0; m < 2; ++m)
#pragma unroll
          for (int dn = 0; dn < 4; ++dn) o[m][dn] *= corr;
        ol[0] *= corr;
        ol[1] *= corr;
      }
#pragma unroll
      for (int m = 0; m < 2; ++m)
#pragma unroll
        for (int n = 0; n < 4; ++n)
#pragma unroll
          for (int r = 0; r < 4; ++r) s[m][n][r] = exp2a(s[m][n][r]);
    }
    // ---- O^T += V^T P^T (permuted k-slots); l via ones-MFMA ----
#pragma unroll
    for (int kk = 0; kk < 2; ++kk) {
      bf16x8 pf[2];
#pragma unroll
      for (int m = 0; m < 2; ++m) {
        uint4v u;
        u[0] = pk2(s[m][2 * kk][0], s[m][2 * kk][1]);
        u[1] = pk2(s[m][2 * kk][2], s[m][2 * kk][3]);
        u[2] = pk2(s[m][2 * kk + 1][0], s[m][2 * kk + 1][1]);
        u[3] = pk2(s[m][2 * kk + 1][2], s[m][2 * kk + 1][3]);
        pf[m] = __builtin_bit_cast(bf16x8, u);
      }
      ol[0] = __builtin_amdgcn_mfma_f32_16x16x32_bf16(ones8, pf[0], ol[0], 0, 0, 0);
      ol[1] = __builtin_amdgcn_mfma_f32_16x16x32_bf16(ones8, pf[1], ol[1], 0, 0, 0);
      const int p0 = (4 * kk + (lg >> 1)) ^ sw;
      const int base0 = lr * 64 + p0 * 8 + (lg & 1) * 4;
      const int base1 = lr * 64 + (p0 ^ 2) * 8 + (lg & 1) * 4;
#pragma unroll
      for (int dn = 0; dn < 4; ++dn) {
        bf16x4 v0 = *(const bf16x4*)&Vb_[base0 + dn * 1024];
        bf16x4 v1 = *(const bf16x4*)&Vb_[base1 + dn * 1024];
        bf16x8 vb = __builtin_shufflevector(v0, v1, 0, 1, 2, 3, 4, 5, 6, 7);
#pragma unroll
        for (int m = 0; m < 2; ++m)
          o[m][dn] = __builtin_amdgcn_mfma_f32_16x16x32_bf16(vb, pf[m], o[m][dn], 0, 0, 0);
      }
    }
    __syncthreads();  // drains next-tile stage; all reads of buf bi done
  }
  // ---- epilogue: o holds O^T[d=16dn+4lg+r][q]; l = ol[m][any r] ----
#pragma unroll
  for (int m = 0; m < 2; ++m) {
    float inv = 1.f / ol[m][0];
    size_t q = rowQ0 + wid * 32 + 16 * m + lr;
#pragma unroll
    for (int dn = 0; dn < 4; ++dn) {
      ushort4v u;
#pragma unroll
      for (int r = 0; r < 4; ++r) u[r] = f2bf(o[m][dn][r] * inv);
      *(ushort4v*)&ctx[q * 1024 + hcol + 16 * dn + 4 * lg] = u;
    }
  }
}

extern "C" void kernel_launch(void* const* d_in, const int* in_sizes, int n_in,
                              void* d_out, int out_size, void* d_ws, size_t ws_size,
                              hipStream_t stream) {
  const float* srcQ = (const float*)d_in[0];
  const float* srcK = (const float*)d_in[1];
  const float* srcV = (const float*)d_in[2];
  const int*   mask = (const int*)d_in[3];
  const float* Wq = (const float*)d_in[4];
  const float* bq = (const float*)d_in[5];
  const float* Wk = (const float*)d_in[6];
  const float* bk = (const float*)d_in[7];
  const float* Wv = (const float*)d_in[8];
  const float* bv = (const float*)d_in[9];
  const float* Wo = (const float*)d_in[10];
  const float* bo = (const float*)d_in[11];
  float* out = (float*)d_out;

  const int M = 8192, N = 1024, Kd = 1024;
  char* ws = (char*)d_ws;
  unsigned short* Xb  = (unsigned short*)(ws);                       // srcX bf16; later ctx
  unsigned short* Qb  = (unsigned short*)(ws + (size_t)(16 << 20));
  unsigned short* Kb  = (unsigned short*)(ws + (size_t)(32 << 20));
  unsigned short* Vt  = (unsigned short*)(ws + (size_t)(48 << 20));  // V^T written by V-GEMM
  unsigned short* Wt  = (unsigned short*)(ws + (size_t)(64 << 20));  // 4 x 2 MiB
  unsigned short* ctx = Xb;

  dim3 tb(256);
  dim3 tg(32, 32);
  transpose_w<<<tg, tb, 0, stream>>>(Wq, Wt + 0 * (1 << 20));
  transpose_w<<<tg, tb, 0, stream>>>(Wk, Wt + 1 * (1 << 20));
  transpose_w<<<tg, tb, 0, stream>>>(Wv, Wt + 2 * (1 << 20));
  transpose_w<<<tg, tb, 0, stream>>>(Wo, Wt + 3 * (1 << 20));

  const int n4 = M * N / 4;
  const int gemm_grid = (M / 128) * (N / 128);

  convert_f2b<<<n4 / 256, 256, 0, stream>>>(srcQ, Xb, n4);
  gemm_bt<unsigned short, false><<<gemm_grid, 256, 0, stream>>>(Xb, Wt + 0 * (1 << 20), bq, Qb, M, N, Kd, LOG2E);
  convert_f2b<<<n4 / 256, 256, 0, stream>>>(srcK, Xb, n4);
  gemm_bt<unsigned short, false><<<gemm_grid, 256, 0, stream>>>(Xb, Wt + 1 * (1 << 20), bk, Kb, M, N, Kd, 1.0f);
  convert_f2b<<<n4 / 256, 256, 0, stream>>>(srcV, Xb, n4);
  gemm_bt<unsigned short, true><<<gemm_grid, 256, 0, stream>>>(Xb, Wt + 2 * (1 << 20), bv, Vt, M, N, Kd, 1.0f);

  attn_kernel<<<1024, 256, 0, stream>>>(Qb, Kb, Vt, mask, ctx);

  gemm_bt<float, false><<<gemm_grid, 256, 0, stream>>>(ctx, Wt + 3 * (1 << 20), bo, out, M, N, Kd, 1.0f);
}

// Round 6
// 229.892 us; speedup vs baseline: 2.6905x; 1.0693x over previous
//
#include <hip/hip_runtime.h>

typedef short bf16x8 __attribute__((ext_vector_type(8)));
typedef short bf16x4 __attribute__((ext_vector_type(4)));
typedef float f32x4 __attribute__((ext_vector_type(4)));
typedef unsigned short ushort8 __attribute__((ext_vector_type(8)));
typedef unsigned short ushort4v __attribute__((ext_vector_type(4)));
typedef unsigned int uint4v __attribute__((ext_vector_type(4)));
typedef float float4v __attribute__((ext_vector_type(4)));

#define LOG2E 1.4426950408889634f
#define MASKED_VAL -14426.950408889634f /* -10000 * log2(e) */
#define DEFER_THR 8.0f

__device__ __forceinline__ unsigned short f2bf(float f) {
  unsigned u = __builtin_bit_cast(unsigned, f);
  u = u + 0x7fffu + ((u >> 16) & 1u);
  return (unsigned short)(u >> 16);
}

// hardware packed f32->bf16 (RNE)
__device__ __forceinline__ unsigned pk2(float a, float b) {
  unsigned r;
  asm("v_cvt_pk_bf16_f32 %0, %1, %2" : "=v"(r) : "v"(a), "v"(b));
  return r;
}

// guaranteed single-instruction exp2
__device__ __forceinline__ float exp2a(float x) {
  float r;
  asm("v_exp_f32 %0, %1" : "=v"(r) : "v"(x));
  return r;
}

__device__ __forceinline__ void gload16(const void* g, void* l) {
  __builtin_amdgcn_global_load_lds(
      (const __attribute__((address_space(1))) unsigned int*)g,
      (__attribute__((address_space(3))) unsigned int*)l, 16, 0, 0);
}

__device__ __forceinline__ void store_out(float* p, float v) { *p = v; }
__device__ __forceinline__ void store_out(unsigned short* p, float v) { *p = f2bf(v); }

// ---------------- W [K][N] fp32 -> Wt [N][K] bf16 ----------------
__global__ __launch_bounds__(256) void transpose_w(const float* __restrict__ W,
                                                   unsigned short* __restrict__ Wt) {
  __shared__ float tile[32][33];
  int bx = blockIdx.x * 32;
  int by = blockIdx.y * 32;
  int tx = threadIdx.x & 31;
  int ty = threadIdx.x >> 5;
#pragma unroll
  for (int j = 0; j < 32; j += 8)
    tile[ty + j][tx] = W[(size_t)(by + ty + j) * 1024 + bx + tx];
  __syncthreads();
#pragma unroll
  for (int j = 0; j < 32; j += 8)
    Wt[(size_t)(bx + ty + j) * 1024 + by + tx] = f2bf(tile[tx][ty + j]);
}

// ---------------- GEMM: C[M,N] = (A[M,K] * Bt[N,K]^T + bias) * scale ----------------
// m97 structure + XCD-aware bm-slice swizzle.
// AF32=true: A is fp32; reg-stage A-tile with fused cvt (kills convert pass).
// VT=true: write V^T layout Vt[(b*1024 + col)][s] (kills transpose_v pass).
template <typename OT, bool VT, bool AF32>
__global__ __launch_bounds__(256) void gemm_bt(const void* __restrict__ Aptr,
                                               const unsigned short* __restrict__ Bt,
                                               const float* __restrict__ bias,
                                               OT* __restrict__ C, int M, int N, int K,
                                               float scale) {
  __shared__ __align__(16) unsigned short As[128 * 32];
  __shared__ __align__(16) unsigned short Bs[128 * 32];
  const int t = threadIdx.x;
  const int nb = N >> 7;
  int bm, bn;
  if ((M >> 7) == 64 && nb == 8) {
    // XCD swizzle: xcd = bid&7 owns bm in [8*xcd, 8*xcd+8), bn-minor
    int x = blockIdx.x & 7, i = blockIdx.x >> 3;
    bm = (x << 3) + (i >> 3);
    bn = i & 7;
  } else {
    bm = blockIdx.x / nb;
    bn = blockIdx.x % nb;
  }
  const int lane = t & 63, wid = t >> 6;
  const int wr = wid >> 1, wc = wid & 1;
  const int lr = lane & 15, lg = lane >> 4;
  f32x4 acc[4][4] = {};
  const size_t baseA = (size_t)(bm * 128) * K;
  const size_t baseB = (size_t)(bn * 128) * K;
  const int c0 = t, c1 = t + 256;
  const int rA0 = c0 >> 2, kA0 = (c0 & 3) * 8;
  const int rA1 = c1 >> 2, kA1 = (c1 & 3) * 8;
  const unsigned short* Ab = (const unsigned short*)Aptr;
  const float* Af = (const float*)Aptr;
  for (int ks = 0; ks < K; ks += 32) {
    if constexpr (AF32) {
      // reg-stage A fp32 -> bf16 (issue loads before the barrier; ds_write after)
      float4v f0 = *(const float4v*)&Af[baseA + (size_t)rA0 * K + ks + kA0];
      float4v f1 = *(const float4v*)&Af[baseA + (size_t)rA0 * K + ks + kA0 + 4];
      float4v f2 = *(const float4v*)&Af[baseA + (size_t)rA1 * K + ks + kA1];
      float4v f3 = *(const float4v*)&Af[baseA + (size_t)rA1 * K + ks + kA1 + 4];
      __syncthreads();
      gload16(&Bt[baseB + (size_t)rA0 * K + ks + kA0], &Bs[c0 * 8]);
      gload16(&Bt[baseB + (size_t)rA1 * K + ks + kA1], &Bs[c1 * 8]);
      uint4v w0, w1;
      w0[0] = pk2(f0[0], f0[1]); w0[1] = pk2(f0[2], f0[3]);
      w0[2] = pk2(f1[0], f1[1]); w0[3] = pk2(f1[2], f1[3]);
      w1[0] = pk2(f2[0], f2[1]); w1[1] = pk2(f2[2], f2[3]);
      w1[2] = pk2(f3[0], f3[1]); w1[3] = pk2(f3[2], f3[3]);
      *(uint4v*)&As[c0 * 8] = w0;
      *(uint4v*)&As[c1 * 8] = w1;
    } else {
      __syncthreads();
      gload16(&Ab[baseA + (size_t)rA0 * K + ks + kA0], &As[c0 * 8]);
      gload16(&Ab[baseA + (size_t)rA1 * K + ks + kA1], &As[c1 * 8]);
      gload16(&Bt[baseB + (size_t)rA0 * K + ks + kA0], &Bs[c0 * 8]);
      gload16(&Bt[baseB + (size_t)rA1 * K + ks + kA1], &Bs[c1 * 8]);
    }
    __syncthreads();
    bf16x8 a[4], b[4];
#pragma unroll
    for (int m = 0; m < 4; ++m)
      a[m] = *(const bf16x8*)&As[(wr * 64 + 16 * m + lr) * 32 + lg * 8];
#pragma unroll
    for (int n = 0; n < 4; ++n)
      b[n] = *(const bf16x8*)&Bs[(wc * 64 + 16 * n + lr) * 32 + lg * 8];
#pragma unroll
    for (int m = 0; m < 4; ++m)
#pragma unroll
      for (int n = 0; n < 4; ++n)
        acc[m][n] = __builtin_amdgcn_mfma_f32_16x16x32_bf16(a[m], b[n], acc[m][n], 0, 0, 0);
  }
  const int rowb = bm * 128 + wr * 64;
  const int colb = bn * 128 + wc * 64;
  if constexpr (VT) {
    // V^T epilogue: row = b*2048 + s; write Vt[(b*1024+col)*2048 + s]
    const int bidx = rowb >> 11;
    const int srow = rowb & 2047;
#pragma unroll
    for (int n = 0; n < 4; ++n) {
      int col = colb + 16 * n + lr;
      float bv = bias[col];
#pragma unroll
      for (int m = 0; m < 4; ++m) {
        int s0 = srow + 16 * m + 4 * lg;
        ushort4v u;
#pragma unroll
        for (int r = 0; r < 4; ++r) u[r] = f2bf((acc[m][n][r] + bv) * scale);
        *(ushort4v*)&C[((size_t)(bidx * 1024 + col)) * 2048 + s0] = u;
      }
    }
  } else {
#pragma unroll
    for (int n = 0; n < 4; ++n) {
      int col = colb + 16 * n + lr;
      float bv = bias[col];
#pragma unroll
      for (int m = 0; m < 4; ++m) {
        int row0 = rowb + 16 * m + 4 * lg;
#pragma unroll
        for (int r = 0; r < 4; ++r) {
          float v = (acc[m][n][r] + bv) * scale;
          store_out(&C[(size_t)(row0 + r) * N + col], v);
        }
      }
    }
  }
}

// ---------------- Flash attention (swapped-operand, P in registers) ----------------
// grid = 1024, XCD-swizzled: logical bid = (g&7)*128 + (g>>3) -> each XCD owns
// 8 contiguous (b,h) groups (K/V slices L2-resident per XCD).
// 4 waves x 32 q-rows (128/block), KVBLK=64. LDS 32KB: [K0|K1|V0|V1].
// Softmax: defer-max (THR=8, shared m_run) folded into QK C-seed; l via ones-MFMA.
// T5: setprio(1) around MFMA clusters.
__global__ __launch_bounds__(256, 4) void attn_kernel(
    const unsigned short* __restrict__ Q, const unsigned short* __restrict__ K,
    const unsigned short* __restrict__ V, const int* __restrict__ mask,
    unsigned short* __restrict__ ctx) {
  __shared__ __align__(16) unsigned short pool[16384];  // 32 KB
  __shared__ int s_any[4];
  unsigned short* Kbuf0 = pool;
  unsigned short* Kbuf1 = pool + 4096;
  unsigned short* Vbuf0 = pool + 8192;
  unsigned short* Vbuf1 = pool + 12288;
  const int g = blockIdx.x;
  const int bid = (g & 7) * 128 + (g >> 3);  // XCD-contiguous logical id
  const int qb = bid & 15, h = (bid >> 4) & 15, b = bid >> 8;
  const int t = threadIdx.x;
  const int lane = t & 63, wid = t >> 6;
  const int lr = lane & 15, lg = lane >> 4;
  const size_t rowQ0 = (size_t)(b * 2048 + qb * 128);
  const int hcol = h * 64;
  const size_t vrow0 = (size_t)((b * 16 + h) * 64) * 2048;

  // per-thread K/V staging bases (pre-swizzled global source, linear LDS dest)
  size_t ksrc[2], vsrc[2];
  int ldso[2];
#pragma unroll
  for (int i = 0; i < 2; ++i) {
    int ci = t + 256 * i;  // 0..511
    int row = ci >> 3, pos = ci & 7;
    ksrc[i] = (size_t)(b * 2048 + row) * 1024 + hcol + ((pos ^ (row & 7)) << 3);
    vsrc[i] = vrow0 + (size_t)row * 2048 + ((pos ^ ((row >> 1) & 7)) << 3);
    ldso[i] = ci * 8;
  }
  // stage Q tile [128 q][64 d] into pool[0..8191] (K region, pre-loop reuse)
#pragma unroll
  for (int i = 0; i < 4; ++i) {
    int ci = t + 256 * i;  // 0..1023
    int row = ci >> 3, pos = ci & 7;
    gload16(&Q[(rowQ0 + row) * 1024 + hcol + ((pos ^ (row & 7)) << 3)], &pool[ci * 8]);
  }
  // block-wide mask scan (8 ints per thread)
  int bad = 0;
  const int* mb = mask + b * 2048;
#pragma unroll
  for (int i = 0; i < 2; ++i) {
    int4 mv = *(const int4*)&mb[t * 8 + i * 4];
    bad |= (mv.x == 0) | (mv.y == 0) | (mv.z == 0) | (mv.w == 0);
  }
  unsigned long long bb = __ballot(bad);
  if (lane == 0) s_any[wid] = (bb != 0ULL);
  __syncthreads();  // Q staged + s_any visible
  // hoist Q fragments: aq[m][kd], q-row = wid*32 + 16m + lr
  bf16x8 aq[2][2];
#pragma unroll
  for (int m = 0; m < 2; ++m)
#pragma unroll
    for (int kd = 0; kd < 2; ++kd) {
      int row = wid * 32 + 16 * m + lr;
      int ch = (4 * kd + lg) ^ (lr & 7);
      aq[m][kd] = *(const bf16x8*)&pool[row * 64 + ch * 8];
    }
  const bool anymask = (s_any[0] | s_any[1] | s_any[2] | s_any[3]) != 0;
  __syncthreads();  // all Q-frag reads done -> pool reusable
  // stage kb=0
#pragma unroll
  for (int i = 0; i < 2; ++i) gload16(&K[ksrc[i]], &Kbuf0[ldso[i]]);
#pragma unroll
  for (int i = 0; i < 2; ++i) gload16(&V[vsrc[i]], &Vbuf0[ldso[i]]);
  __syncthreads();  // K0/V0 ready

  float m_run = 0.f;
  f32x4 o[2][4] = {};
  f32x4 ol[2] = {};
  const short oneb = 0x3F80;
  const bf16x8 ones8 = {oneb, oneb, oneb, oneb, oneb, oneb, oneb, oneb};
  const int ch0 = (lg ^ (lr & 7)) * 8;
  const int ch1 = ((4 + lg) ^ (lr & 7)) * 8;
  const int sw = lr >> 1;

  for (int kb = 0; kb < 32; ++kb) {
    const int bi = kb & 1;
    const unsigned short* Kb_ = bi ? Kbuf1 : Kbuf0;
    const unsigned short* Vb_ = bi ? Vbuf1 : Vbuf0;
    unsigned short* Kn_ = bi ? Kbuf0 : Kbuf1;
    unsigned short* Vn_ = bi ? Vbuf0 : Vbuf1;
    // issue next-tile stage first (lands before end-of-iter barrier)
    if (kb + 1 < 32) {
      const size_t ko = (size_t)(kb + 1) * 64 * 1024;
      const size_t vo = (size_t)(kb + 1) * 64;
#pragma unroll
      for (int i = 0; i < 2; ++i) gload16(&K[ksrc[i] + ko], &Kn_[ldso[i]]);
#pragma unroll
      for (int i = 0; i < 2; ++i) gload16(&V[vsrc[i] + vo], &Vn_[ldso[i]]);
    }
    // ---- S^T = K Q^T, pre-shifted by -m_run via C-seed ----
    f32x4 s[2][4];
    const f32x4 cm = {-m_run, -m_run, -m_run, -m_run};
    __builtin_amdgcn_s_setprio(1);
#pragma unroll
    for (int n = 0; n < 4; ++n) {
      bf16x8 k0 = *(const bf16x8*)&Kb_[(16 * n + lr) * 64 + ch0];
      bf16x8 k1 = *(const bf16x8*)&Kb_[(16 * n + lr) * 64 + ch1];
      f32x4 t0 = __builtin_amdgcn_mfma_f32_16x16x32_bf16(k0, aq[0][0], cm, 0, 0, 0);
      s[0][n] = __builtin_amdgcn_mfma_f32_16x16x32_bf16(k1, aq[0][1], t0, 0, 0, 0);
      f32x4 t1 = __builtin_amdgcn_mfma_f32_16x16x32_bf16(k0, aq[1][0], cm, 0, 0, 0);
      s[1][n] = __builtin_amdgcn_mfma_f32_16x16x32_bf16(k1, aq[1][1], t1, 0, 0, 0);
    }
    __builtin_amdgcn_s_setprio(0);
    if (anymask) {
      const int* mrow = mb + kb * 64;
#pragma unroll
      for (int n = 0; n < 4; ++n) {
        int4 mv = *(const int4*)&mrow[16 * n + 4 * lg];
        int mm[4] = {mv.x, mv.y, mv.z, mv.w};
#pragma unroll
        for (int r = 0; r < 4; ++r)
          if (mm[r] == 0) {
            s[0][n][r] = MASKED_VAL - m_run;
            s[1][n][r] = MASKED_VAL - m_run;
          }
      }
    }
    // ---- deferred-max online softmax (base-2, shifted space, shared m_run) ----
    {
      float pmax = s[0][0][0];
#pragma unroll
      for (int m = 0; m < 2; ++m)
#pragma unroll
        for (int n = 0; n < 4; ++n) {
          float a = fmaxf(fmaxf(s[m][n][0], s[m][n][1]), fmaxf(s[m][n][2], s[m][n][3]));
          pmax = fmaxf(pmax, a);
        }
      if (__any(pmax > DEFER_THR)) {  // rare slow path: shift + rescale
        float mx = fmaxf(pmax, __shfl_xor(pmax, 16));
        mx = fmaxf(mx, __shfl_xor(mx, 32));
        float corr = exp2a(-mx);
        m_run += mx;
#pragma unroll
        for (int m = 0; m < 2; ++m)
#pragma unroll
          for (int n = 0; n < 4; ++n)
#pragma unroll
            for (int r = 0; r < 4; ++r) s[m][n][r] -= mx;
#pragma unroll
        for (int m = 0; m < 2; ++m)
#pragma unroll
          for (int dn = 0; dn < 4; ++dn) o[m][dn] *= corr;
        ol[0] *= corr;
        ol[1] *= corr;
      }
#pragma unroll
      for (int m = 0; m < 2; ++m)
#pragma unroll
        for (int n = 0; n < 4; ++n)
#pragma unroll
          for (int r = 0; r < 4; ++r) s[m][n][r] = exp2a(s[m][n][r]);
    }
    // ---- O^T += V^T P^T (permuted k-slots); l via ones-MFMA ----
#pragma unroll
    for (int kk = 0; kk < 2; ++kk) {
      bf16x8 pf[2];
#pragma unroll
      for (int m = 0; m < 2; ++m) {
        uint4v u;
        u[0] = pk2(s[m][2 * kk][0], s[m][2 * kk][1]);
        u[1] = pk2(s[m][2 * kk][2], s[m][2 * kk][3]);
        u[2] = pk2(s[m][2 * kk + 1][0], s[m][2 * kk + 1][1]);
        u[3] = pk2(s[m][2 * kk + 1][2], s[m][2 * kk + 1][3]);
        pf[m] = __builtin_bit_cast(bf16x8, u);
      }
      __builtin_amdgcn_s_setprio(1);
      ol[0] = __builtin_amdgcn_mfma_f32_16x16x32_bf16(ones8, pf[0], ol[0], 0, 0, 0);
      ol[1] = __builtin_amdgcn_mfma_f32_16x16x32_bf16(ones8, pf[1], ol[1], 0, 0, 0);
      const int p0 = (4 * kk + (lg >> 1)) ^ sw;
      const int base0 = lr * 64 + p0 * 8 + (lg & 1) * 4;
      const int base1 = lr * 64 + (p0 ^ 2) * 8 + (lg & 1) * 4;
#pragma unroll
      for (int dn = 0; dn < 4; ++dn) {
        bf16x4 v0 = *(const bf16x4*)&Vb_[base0 + dn * 1024];
        bf16x4 v1 = *(const bf16x4*)&Vb_[base1 + dn * 1024];
        bf16x8 vb = __builtin_shufflevector(v0, v1, 0, 1, 2, 3, 4, 5, 6, 7);
#pragma unroll
        for (int m = 0; m < 2; ++m)
          o[m][dn] = __builtin_amdgcn_mfma_f32_16x16x32_bf16(vb, pf[m], o[m][dn], 0, 0, 0);
      }
      __builtin_amdgcn_s_setprio(0);
    }
    __syncthreads();  // drains next-tile stage; all reads of buf bi done
  }
  // ---- epilogue: o holds O^T[d=16dn+4lg+r][q]; l = ol[m][any r] ----
#pragma unroll
  for (int m = 0; m < 2; ++m) {
    float inv = 1.f / ol[m][0];
    size_t q = rowQ0 + wid * 32 + 16 * m + lr;
#pragma unroll
    for (int dn = 0; dn < 4; ++dn) {
      ushort4v u;
#pragma unroll
      for (int r = 0; r < 4; ++r) u[r] = f2bf(o[m][dn][r] * inv);
      *(ushort4v*)&ctx[q * 1024 + hcol + 16 * dn + 4 * lg] = u;
    }
  }
}

extern "C" void kernel_launch(void* const* d_in, const int* in_sizes, int n_in,
                              void* d_out, int out_size, void* d_ws, size_t ws_size,
                              hipStream_t stream) {
  const float* srcQ = (const float*)d_in[0];
  const float* srcK = (const float*)d_in[1];
  const float* srcV = (const float*)d_in[2];
  const int*   mask = (const int*)d_in[3];
  const float* Wq = (const float*)d_in[4];
  const float* bq = (const float*)d_in[5];
  const float* Wk = (const float*)d_in[6];
  const float* bk = (const float*)d_in[7];
  const float* Wv = (const float*)d_in[8];
  const float* bv = (const float*)d_in[9];
  const float* Wo = (const float*)d_in[10];
  const float* bo = (const float*)d_in[11];
  float* out = (float*)d_out;

  const int M = 8192, N = 1024, Kd = 1024;
  char* ws = (char*)d_ws;
  unsigned short* ctx = (unsigned short*)(ws);                       // 16 MiB
  unsigned short* Qb  = (unsigned short*)(ws + (size_t)(16 << 20));
  unsigned short* Kb  = (unsigned short*)(ws + (size_t)(32 << 20));
  unsigned short* Vt  = (unsigned short*)(ws + (size_t)(48 << 20));  // V^T from V-GEMM
  unsigned short* Wt  = (unsigned short*)(ws + (size_t)(64 << 20));  // 4 x 2 MiB

  dim3 tb(256);
  dim3 tg(32, 32);
  transpose_w<<<tg, tb, 0, stream>>>(Wq, Wt + 0 * (1 << 20));
  transpose_w<<<tg, tb, 0, stream>>>(Wk, Wt + 1 * (1 << 20));
  transpose_w<<<tg, tb, 0, stream>>>(Wv, Wt + 2 * (1 << 20));
  transpose_w<<<tg, tb, 0, stream>>>(Wo, Wt + 3 * (1 << 20));

  const int gemm_grid = (M / 128) * (N / 128);  // 512

  gemm_bt<unsigned short, false, true><<<gemm_grid, 256, 0, stream>>>(srcQ, Wt + 0 * (1 << 20), bq, Qb, M, N, Kd, LOG2E);
  gemm_bt<unsigned short, false, true><<<gemm_grid, 256, 0, stream>>>(srcK, Wt + 1 * (1 << 20), bk, Kb, M, N, Kd, 1.0f);
  gemm_bt<unsigned short, true,  true><<<gemm_grid, 256, 0, stream>>>(srcV, Wt + 2 * (1 << 20), bv, Vt, M, N, Kd, 1.0f);

  attn_kernel<<<1024, 256, 0, stream>>>(Qb, Kb, Vt, mask, ctx);

  gemm_bt<float, false, false><<<gemm_grid, 256, 0, stream>>>(ctx, Wt + 3 * (1 << 20), bo, out, M, N, Kd, 1.0f);
}